// Round 8
// baseline (182.040 us; speedup 1.0000x reference)
//
#include <hip/hip_runtime.h>
#include <hip/hip_bf16.h>

#define NN 10240
#define LL 80
#define BB 128

typedef _Float16 half8 __attribute__((ext_vector_type(8)));
typedef _Float16 half2v __attribute__((ext_vector_type(2)));
typedef float f32x4 __attribute__((ext_vector_type(4)));

#define GLD16(gptr, lptr)                                                        \
  __builtin_amdgcn_global_load_lds(                                              \
      (const __attribute__((address_space(1))) void*)(gptr),                     \
      (__attribute__((address_space(3))) void*)(lptr), 16, 0, 0)

__device__ __forceinline__ float dot2f(half2v a, half2v b, float c) {
#if __has_builtin(__builtin_amdgcn_fdot2)
  return __builtin_amdgcn_fdot2(a, b, c, false);
#else
  return c + (float)a.x * (float)b.x + (float)a.y * (float)b.y;
#endif
}
__device__ __forceinline__ half2v u2h(unsigned int u) { half2v r; __builtin_memcpy(&r, &u, 4); return r; }
__device__ __forceinline__ unsigned int h2u(half2v h) { unsigned int u; __builtin_memcpy(&u, &h, 4); return u; }
// row offset (f16 units): 144B stride -> 16B-aligned rows (b128-legal)
__device__ __forceinline__ int roff(int r) { return r * 72; }

// 4 dwords (8 ch) of logit dot with pre-hoisted att regs: acc += att . lrelu(xl + xr)
__device__ __forceinline__ float dotq4r(uint4 a, uint4 b, const half2v* atv, int qb, float acc) {
  const half2v c02 = {(_Float16)0.2f, (_Float16)0.2f};
  unsigned int aa[4] = {a.x, a.y, a.z, a.w};
  unsigned int bb[4] = {b.x, b.y, b.z, b.w};
#pragma unroll
  for (int j = 0; j < 4; ++j) {
    half2v e = u2h(aa[j]) + u2h(bb[j]);
    half2v l = __builtin_elementwise_max(e, e * c02);
    acc = dot2f(l, atv[qb + j], acc);
  }
  return acc;
}

// ================= prep_all: gate_scale (4 nodes/block, vectorized) + transposes ================
__global__ __launch_bounds__(256) void prep_all(
    const float* __restrict__ x, const float* __restrict__ rel,
    const float* __restrict__ w1, const float* __restrict__ b1,
    const float* __restrict__ w2, const float* __restrict__ b2,
    const float* __restrict__ Wl1, const float* __restrict__ Wr1,
    const float* __restrict__ Wl2, const float* __restrict__ Wr2,
    const float* __restrict__ bl1, const float* __restrict__ br1,
    const float* __restrict__ att1,
    _Float16* __restrict__ h0, _Float16* __restrict__ Wt1,
    _Float16* __restrict__ Wt2cat,
    float* __restrict__ biasc, _Float16* __restrict__ att_h) {
  __shared__ float tile[32][33];
  int bid = blockIdx.x;
  int tid = threadIdx.x;
  if (bid < 2560) {
    int wave = tid >> 6, l = tid & 63;
    int n = bid * 4 + wave;
    float r0 = rel[n * 3 + 0], r1 = rel[n * 3 + 1], r2 = rel[n * 3 + 2];
    float v = r0 * w1[l] + r1 * w1[64 + l] + r2 * w1[128 + l] + b1[l];
    v = v > 0.f ? v : 0.f;
    v *= w2[l];
    for (int d = 32; d; d >>= 1) v += __shfl_down(v, d, 64);
    float s = __shfl(v, 0, 64);
    float g = 1.f / (1.f + __expf(-(s + b2[0])));
    const float4* xr = (const float4*)(x + (size_t)n * 768);
    _Float16* hr = h0 + (size_t)n * 768;
#pragma unroll
    for (int i = 0; i < 3; ++i) {
      int f = i * 64 + l;
      float4 xv = xr[f];
      half2v p0 = {(_Float16)(xv.x * g), (_Float16)(xv.y * g)};
      half2v p1 = {(_Float16)(xv.z * g), (_Float16)(xv.w * g)};
      uint2 ov = {h2u(p0), h2u(p1)};
      *(uint2*)&hr[f * 4] = ov;
    }
    return;
  }
  int r = bid - 2560;
  const float* W;
  _Float16* Wt;
  int K, Nc, bx, by;
  if (r < 384)      { W = Wl1; Wt = Wt1;                          K = 768; Nc = 512; bx = r % 16;       by = r / 16; }
  else if (r < 768) { W = Wr1; Wt = Wt1 + (size_t)512 * 768;      K = 768; Nc = 512; bx = (r-384) % 16; by = (r-384) / 16; }
  else if (r < 896) { W = Wl2; Wt = Wt2cat;                       K = 512; Nc = 256; bx = (r-768) % 8;  by = (r-768) / 8; }
  else if (r < 1024){ W = Wr2; Wt = Wt2cat + (size_t)256 * 512;   K = 512; Nc = 256; bx = (r-896) % 8;  by = (r-896) / 8; }
  else {
    for (int i = tid; i < 1024; i += 256) biasc[i] = (i < 512) ? bl1[i] : br1[i - 512];
    for (int i = tid; i < 512; i += 256) att_h[i] = (_Float16)att1[i];
    return;
  }
  int n0 = bx * 32, k0 = by * 32;
  int c = tid & 31, rr = tid >> 5;
#pragma unroll
  for (int p = 0; p < 4; ++p) {
    int rw = p * 8 + rr;
    tile[rw][c] = W[(size_t)(k0 + rw) * Nc + n0 + c];
  }
  __syncthreads();
#pragma unroll
  for (int p = 0; p < 4; ++p) {
    int rw = p * 8 + rr;
    Wt[(size_t)(n0 + rw) * K + k0 + c] = (_Float16)tile[c][rw];
  }
}

// ================= fused gemm1 + GATv2 layer-1: TWO HEADS PER BLOCK ================
// block = (head-pair, dialogue): hp = bx>>7 (0..3), b = bx&127. grid 512 = 2/CU, fully resident.
// GEMM: M=80, N=256 (h0-xl|h0-xr|h1-xl|h1-xr), K=768, BK=32, 24 slabs, 2-phase dbuf.
//   Each wave owns 2 n-tiles (w, w+8) -> A-fragments feed 2 MFMAs: block LDS reads
//   56/slab vs 96 (R6, 1 head) per head-pair -> -42% LDS-read pipe (the measured wall).
//   Swizzle/staging = proven R6-g2 pattern (seg=(lane&3)^((lane>>3)&3), read lk^((lr>>1)&3)).
// GAT: epilogue writes BOTH heads' xl/xr/xlT from acc[m][hj] (acc dead before the
//   register-heavy logit phase -> no R4-style spill), then per-head sequential:
//   logits -> softmax+zeroP -> scatter -> P-MFMA -> h1.
// LDS 74240 B (2 blocks/CU):
//   staging: Ab 2x5120 @0, Bb 2x16384 @10240 -> 43008 (dead after loop)
//   GAT: xl0@0 xr0@11520 xl1@23040 xr1@34560 (11520 each), logit@46080(4160),
//        src8@50240(1040), hub@51280(320), xlT0@51600(11264), xlT1@62864(11264) ->74128
//   P overlays @0 (16640; tramples only dead xl0/xr0-part)
__global__ __launch_bounds__(512, 6) void gemm1gat1(
    const _Float16* __restrict__ h0, const _Float16* __restrict__ Wt1,
    const float* __restrict__ biasc, const _Float16* __restrict__ att_h,
    const float* __restrict__ bias1, _Float16* __restrict__ h1) {
  __shared__ __align__(16) char smem[74240];
  _Float16* Ab = (_Float16*)smem;
  _Float16* Bb = (_Float16*)(smem + 10240);
  _Float16* s_xl0 = (_Float16*)smem;
  _Float16* s_xr0 = (_Float16*)(smem + 11520);
  _Float16* s_xl1 = (_Float16*)(smem + 23040);
  _Float16* s_xr1 = (_Float16*)(smem + 34560);
  float* s_logit = (float*)(smem + 46080);
  signed char* s_src8 = (signed char*)(smem + 50240);
  float* s_hub = (float*)(smem + 51280);
  _Float16* s_xlT0 = (_Float16*)(smem + 51600);
  _Float16* s_xlT1 = (_Float16*)(smem + 62864);
  _Float16* s_P = (_Float16*)smem;   // overlays xl0/xr0-part after logits

  int bx = blockIdx.x;
  int hp = bx >> 7, b = bx & 127;
  int base = b * LL;
  int tid = threadIdx.x;
  int wave = tid >> 6, lane = tid & 63;
  int lr = lane & 15, lk = lane >> 4;

  // ---- staging pointers (R6-g2 proven pattern; seg = (lane&3)^((lane>>3)&3)) ----
  int seg8 = ((lane & 3) ^ ((lane >> 3) & 3)) * 8;
  const _Float16* aP = h0;
  if (wave < 5) {
    int c = wave * 64 + lane;                 // 0..319: row = c>>2
    aP = h0 + (size_t)(base + (c >> 2)) * 768 + seg8;
  }
  // B: 256 tile-rows. r<64: h0-xl | 64..127: h0-xr | 128..191: h1-xl | 192..255: h1-xr
  int c0 = wave * 128 + lane;
  int r0 = c0 >> 2, r1 = (c0 + 64) >> 2;
  int rh0 = r0 & 127, rh1 = r1 & 127;
  int hh0 = hp * 2 + (r0 >> 7), hh1 = hp * 2 + (r1 >> 7);
  int w0 = (rh0 < 64) ? (hh0 * 64 + rh0) : (512 + hh0 * 64 + (rh0 - 64));
  int w1 = (rh1 < 64) ? (hh1 * 64 + rh1) : (512 + hh1 * 64 + (rh1 - 64));
  const _Float16* bP0 = Wt1 + (size_t)w0 * 768 + seg8;
  const _Float16* bP1 = Wt1 + (size_t)w1 * 768 + seg8;
  int xk8 = (lk ^ ((lr >> 1) & 3)) * 8;

  f32x4 acc[5][2] = {};
  if (wave < 5) GLD16(aP, Ab + wave * 512);
  GLD16(bP0, Bb + wave * 1024);
  GLD16(bP1, Bb + wave * 1024 + 512);
  __syncthreads();
  for (int t = 0; t < 24; ++t) {
    int cur = t & 1;
    if (t < 23) {
      int k0 = (t + 1) * 32;
      int nb = cur ^ 1;
      if (wave < 5) GLD16(aP + k0, Ab + nb * 2560 + wave * 512);
      GLD16(bP0 + k0, Bb + nb * 8192 + wave * 1024);
      GLD16(bP1 + k0, Bb + nb * 8192 + wave * 1024 + 512);
    }
    const _Float16* Ac = Ab + cur * 2560;
    const _Float16* Bc = Bb + cur * 8192;
    half8 bf0 = *(const half8*)(Bc + (wave * 16 + lr) * 32 + xk8);
    half8 bf1 = *(const half8*)(Bc + ((wave + 8) * 16 + lr) * 32 + xk8);
#pragma unroll
    for (int m = 0; m < 5; ++m) {
      half8 af = *(const half8*)(Ac + (m * 16 + lr) * 32 + xk8);
      acc[m][0] = __builtin_amdgcn_mfma_f32_16x16x32_f16(af, bf0, acc[m][0], 0, 0, 0);
      acc[m][1] = __builtin_amdgcn_mfma_f32_16x16x32_f16(af, bf1, acc[m][1], 0, 0, 0);
    }
    __syncthreads();
  }
  // ---- epilogue: both heads' xl/xr (+bias) + xlT; adjacency build ----
  {
    int c2 = wave * 16 + lr;          // 0..127 within head
    bool isxl = c2 < 64;
    int cc = isxl ? c2 : c2 - 64;
#pragma unroll
    for (int hj = 0; hj < 2; ++hj) {
      int h = hp * 2 + hj;
      float bb = biasc[(isxl ? 0 : 512) + h * 64 + cc];
      _Float16* dst = hj ? (isxl ? s_xl1 : s_xr1) : (isxl ? s_xl0 : s_xr0);
      _Float16* xlT = hj ? s_xlT1 : s_xlT0;
#pragma unroll
      for (int m = 0; m < 5; ++m)
#pragma unroll
        for (int rg = 0; rg < 4; ++rg) {
          int row = m * 16 + lk * 4 + rg;
          _Float16 hv = (_Float16)(acc[m][hj][rg] + bb);
          dst[roff(row) + cc] = hv;
          if (isxl) xlT[cc * 88 + row] = hv;
        }
    }
  }
  if (tid < 79) {
    int d = tid;
    signed char list[13];
    int c = 0;
    list[c++] = (signed char)d;
    if (d > 0) list[c++] = (signed char)(d - 1);
    if (d + 1 < 79) list[c++] = (signed char)(d + 1);
    list[c++] = 79;
    for (int j = d & 7; j < 80; j += 8)
      if (j != d && j != 79) list[c++] = (signed char)j;
    for (int i = c; i < 13; ++i) list[i] = -1;
#pragma unroll
    for (int i = 0; i < 13; ++i) s_src8[i * 80 + d] = list[i];
  }
  __syncthreads();

  // ---- per-head GAT: logits -> softmax+zeroP -> scatter -> P-MFMA ----
  for (int hj = 0; hj < 2; ++hj) {
    int h = hp * 2 + hj;
    _Float16* xlC = hj ? s_xl1 : s_xl0;
    _Float16* xrC = hj ? s_xr1 : s_xr0;
    _Float16* xlTC = hj ? s_xlT1 : s_xlT0;
    const unsigned int* pat = (const unsigned int*)(att_h + h * 64);
    half2v atv[32];
#pragma unroll
    for (int q = 0; q < 32; ++q) atv[q] = u2h(__builtin_amdgcn_readfirstlane(pat[q]));
    // logits: dst-grouped, xr cached in regs, xl streamed b128
    if (tid < 474) {
      int d = tid / 6, io = tid % 6;
      const uint4* pxr = (const uint4*)(xrC + roff(d));
      uint4 xrr[8];
#pragma unroll
      for (int q = 0; q < 8; ++q) xrr[q] = pxr[q];
#pragma unroll
      for (int k = 0; k < 3; ++k) {
        int i = io + 6 * k;
        if (i < 13) {
          int src = s_src8[i * 80 + d];
          if (src < 0) {
            s_logit[i * 80 + d] = -3e38f;
          } else {
            const uint4* pxl = (const uint4*)(xlC + roff(src));
            float a2 = 0.f;
#pragma unroll
            for (int q = 0; q < 8; ++q) a2 = dotq4r(pxl[q], xrr[q], atv, q * 4, a2);
            s_logit[i * 80 + d] = a2;
          }
        }
      }
    } else {
      int j = tid - 474;
      const uint4* pxr = (const uint4*)(xrC + roff(79));
      uint4 xrr[8];
#pragma unroll
      for (int q = 0; q < 8; ++q) xrr[q] = pxr[q];
#pragma unroll
      for (int k = 0; k < 3; ++k) {
        int s = j + 38 * k;
        if (s < 80) {
          const uint4* pxl = (const uint4*)(xlC + roff(s));
          float a2 = 0.f;
#pragma unroll
          for (int q = 0; q < 8; ++q) a2 = dotq4r(pxl[q], xrr[q], atv, q * 4, a2);
          s_hub[s] = a2;
        }
      }
    }
    __syncthreads();

    // softmax into regs + zero dense P (overlay region; xl0/xr0-part now dead)
    {
      uint4 z4 = {0u, 0u, 0u, 0u};
      for (int z = tid; z < 1040; z += 512) ((uint4*)smem)[z] = z4;
    }
    float va[13], inv_d = 0.f;
    bool isd = tid < 79;
    if (isd) {
      int d = tid;
      float m = -3e38f;
#pragma unroll
      for (int i = 0; i < 13; ++i) { va[i] = s_logit[i * 80 + d]; m = fmaxf(m, va[i]); }
      float sum = 0.f;
#pragma unroll
      for (int i = 0; i < 13; ++i) { va[i] = __expf(va[i] - m); sum += va[i]; }
      inv_d = 1.f / sum;
    }
    float he0 = 0.f, he1 = 0.f, hinv = 0.f;
    if (wave == 7) {
      int l = lane;
      float v0 = s_hub[l];
      float v1 = (l < 16) ? s_hub[64 + l] : -3e38f;
      float m = fmaxf(v0, v1);
      for (int d = 32; d; d >>= 1) m = fmaxf(m, __shfl_xor(m, d, 64));
      he0 = __expf(v0 - m);
      he1 = (l < 16) ? __expf(v1 - m) : 0.f;
      float sum = he0 + he1;
      for (int d = 32; d; d >>= 1) sum += __shfl_xor(sum, d, 64);
      hinv = 1.f / sum;
    }
    __syncthreads();

    // scatter alphas into P (f16)
    if (isd) {
      int d = tid;
#pragma unroll
      for (int i = 0; i < 13; ++i) {
        int src = s_src8[i * 80 + d];
        if (src >= 0) s_P[d * 104 + src] = (_Float16)(va[i] * inv_d);
      }
    }
    if (wave == 7) {
      int l = lane;
      s_P[79 * 104 + l] = (_Float16)(he0 * hinv);
      if (l < 16) s_P[79 * 104 + 64 + l] = (_Float16)(he1 * hinv);
    }
    __syncthreads();

    // MFMA aggregation out[80x64] = P[80x80(pad96)] @ xlT^T; ELU; h1
    {
      int nt = (wave < 4) ? 3 : 2;
      int tb = (wave < 4) ? wave * 3 : 12 + (wave - 4) * 2;
      for (int tt = 0; tt < nt; ++tt) {
        int t = tb + tt;
        int m = t >> 2, n = t & 3;
        f32x4 a = {};
#pragma unroll
        for (int kc = 0; kc < 3; ++kc) {
          half8 af = *(const half8*)(s_P + (m * 16 + lr) * 104 + kc * 32 + lk * 8);
          half8 bf = *(const half8*)(xlTC + (n * 16 + lr) * 88 + kc * 32 + lk * 8);
          a = __builtin_amdgcn_mfma_f32_16x16x32_f16(af, bf, a, 0, 0, 0);
        }
        int c = n * 16 + lr;
        float bb = bias1[h * 64 + c];
#pragma unroll
        for (int rg = 0; rg < 4; ++rg) {
          int d = m * 16 + lk * 4 + rg;
          float v = a[rg] + bb;
          v = v > 0.f ? v : __expf(v) - 1.f;
          h1[(size_t)(base + d) * 512 + h * 64 + c] = (_Float16)v;
        }
      }
    }
    __syncthreads();
  }
}

// ================= gemm2a: xl2 = h1 @ Wl2 + bl2 (unchanged from R7) ==============
__global__ __launch_bounds__(256) void gemm2a(
    const _Float16* __restrict__ h1, const _Float16* __restrict__ Bt,
    const float* __restrict__ bl2, _Float16* __restrict__ xl2) {
  __shared__ __align__(16) char smem[16384];
  _Float16* Ab = (_Float16*)smem;            // 2 x 2048 f16
  _Float16* Bb = (_Float16*)(smem + 8192);   // 2 x 2048 f16
  int bx = blockIdx.x;
  int mb = bx >> 2, nb = bx & 3;
  int tid = threadIdx.x;
  int wave = tid >> 6, lane = tid & 63;
  int lr = lane & 15, lk = lane >> 4;
  int seg8 = ((lane & 3) ^ ((lane >> 3) & 3)) * 8;
  int row = tid >> 2;               // 0..63
  const _Float16* aP = h1 + (size_t)(mb * 64 + row) * 512 + seg8;
  const _Float16* bP = Bt + (size_t)(nb * 64 + row) * 512 + seg8;
  int xk8 = (lk ^ ((lr >> 1) & 3)) * 8;
  f32x4 acc[4] = {};
  GLD16(aP, Ab + wave * 512);
  GLD16(bP, Bb + wave * 512);
  __syncthreads();
  for (int t = 0; t < 16; ++t) {
    int cur = t & 1;
    if (t < 15) {
      int k0 = (t + 1) * 32;
      int nbuf = cur ^ 1;
      GLD16(aP + k0, Ab + nbuf * 2048 + wave * 512);
      GLD16(bP + k0, Bb + nbuf * 2048 + wave * 512);
    }
    const _Float16* Ac = Ab + cur * 2048;
    const _Float16* Bc = Bb + cur * 2048;
    half8 bf = *(const half8*)(Bc + (wave * 16 + lr) * 32 + xk8);
#pragma unroll
    for (int m = 0; m < 4; ++m) {
      half8 af = *(const half8*)(Ac + (m * 16 + lr) * 32 + xk8);
      acc[m] = __builtin_amdgcn_mfma_f32_16x16x32_f16(af, bf, acc[m], 0, 0, 0);
    }
    __syncthreads();
  }
  int col = nb * 64 + wave * 16 + lr;
  float bb = bl2[col];
#pragma unroll
  for (int m = 0; m < 4; ++m)
#pragma unroll
    for (int rg = 0; rg < 4; ++rg) {
      int r = mb * 64 + m * 16 + lk * 4 + rg;
      xl2[(size_t)r * 256 + col] = (_Float16)(acc[m][rg] + bb);
    }
}

// ================= gat2ln: per-dialogue attention + LN (unchanged from R7) ==============
#define PX 264
__global__ __launch_bounds__(512) void gat2ln(
    const _Float16* __restrict__ h1, const _Float16* __restrict__ xl2,
    const _Float16* __restrict__ Bt, const float* __restrict__ br2,
    const float* __restrict__ att2, const float* __restrict__ bias2,
    const float* __restrict__ ln_g, const float* __restrict__ ln_b,
    float* __restrict__ out) {
  __shared__ __align__(16) _Float16 s_x[80 * PX];   // 42240 B
  __shared__ _Float16 s_att[256];
  __shared__ _Float16 s_xr[256];
  __shared__ float s_red[80];
  __shared__ float s_sum[4], s_sq[4];

  int b = blockIdx.x;
  int tid = threadIdx.x;
  int wave = tid >> 6, lane = tid & 63;

  if (tid < 256) s_att[tid] = (_Float16)att2[tid];
  // stage xl2[b] (80x256 f16) into s_x [80][PX] via b128
  for (int t = tid; t < 2560; t += 512) {
    int row = t >> 5, q = t & 31;
    uint4 v = *(const uint4*)(xl2 + ((size_t)(b * 80 + row)) * 256 + q * 8);
    *(uint4*)(s_x + row * PX + q * 8) = v;
  }
  // xr row 79: c = tid>>1, k-half = tid&1; global dots on Bt rows 256+c (L2-hot)
  {
    int c = tid >> 1, kh = tid & 1;
    const uint4* wr = (const uint4*)(Bt + (size_t)(256 + c) * 512 + kh * 256);
    const uint4* hq = (const uint4*)(h1 + (size_t)(b * 80 + 79) * 512 + kh * 256);
    float s = 0.f;
#pragma unroll 8
    for (int q = 0; q < 32; ++q) {
      uint4 ua = hq[q], uw = wr[q];
      s = dot2f(u2h(ua.x), u2h(uw.x), s);
      s = dot2f(u2h(ua.y), u2h(uw.y), s);
      s = dot2f(u2h(ua.z), u2h(uw.z), s);
      s = dot2f(u2h(ua.w), u2h(uw.w), s);
    }
    s += __shfl_xor(s, 1, 64);
    if (kh == 0) s_xr[c] = (_Float16)(s + br2[c]);
  }
  __syncthreads();
  if (tid < 160) {
    int r = tid >> 1, hf = tid & 1;
    const half2v* xa = (const half2v*)(s_x + r * PX + hf * 128);
    const half2v* xr = (const half2v*)(s_xr + hf * 128);
    const half2v* at = (const half2v*)(s_att + hf * 128);
    float lg = 0.f;
    const half2v c02 = {(_Float16)0.2f, (_Float16)0.2f};
#pragma unroll
    for (int q = 0; q < 64; ++q) {
      half2v e = xa[q] + xr[q];
      half2v l = __builtin_elementwise_max(e, e * c02);
      lg = dot2f(l, at[q], lg);
    }
    lg += __shfl_xor(lg, 1, 64);
    if (hf == 0) s_red[r] = lg;
  }
  __syncthreads();
  if (wave == 7) {
    float v0 = s_red[lane];
    float v1 = (lane < 16) ? s_red[64 + lane] : -3e38f;
    float m = fmaxf(v0, v1);
    for (int d = 32; d; d >>= 1) m = fmaxf(m, __shfl_xor(m, d, 64));
    float e0 = __expf(v0 - m);
    float e1 = (lane < 16) ? __expf(v1 - m) : 0.f;
    float sum = e0 + e1;
    for (int d = 32; d; d >>= 1) sum += __shfl_xor(sum, d, 64);
    float inv = 1.f / sum;
    s_red[lane] = e0 * inv;
    if (lane < 16) s_red[64 + lane] = e1 * inv;
  }
  __syncthreads();
  float v = 0.f;
  if (tid < 256) {
    float a = 0.f;
#pragma unroll
    for (int r = 0; r < 80; ++r) a += s_red[r] * (float)s_x[r * PX + tid];
    v = a + bias2[tid];
    float p = v;
    for (int d = 32; d; d >>= 1) p += __shfl_down(p, d, 64);
    if (lane == 0) s_sum[wave] = p;
    float q = v * v;
    for (int d = 32; d; d >>= 1) q += __shfl_down(q, d, 64);
    if (lane == 0) s_sq[wave] = q;
  }
  __syncthreads();
  if (tid < 256) {
    float mu = (s_sum[0] + s_sum[1] + s_sum[2] + s_sum[3]) * (1.f / 256.f);
    float ex2 = (s_sq[0] + s_sq[1] + s_sq[2] + s_sq[3]) * (1.f / 256.f);
    float var = ex2 - mu * mu;
    float r = rsqrtf(var + 1e-5f);
    out[b * 256 + tid] = (v - mu) * r * ln_g[tid] + ln_b[tid];
  }
}

extern "C" void kernel_launch(void* const* d_in, const int* in_sizes, int n_in,
                              void* d_out, int out_size, void* d_ws, size_t ws_size,
                              hipStream_t stream) {
  const float* x      = (const float*)d_in[0];
  const float* rel    = (const float*)d_in[1];
  const float* w1     = (const float*)d_in[2];
  const float* b1     = (const float*)d_in[3];
  const float* w2     = (const float*)d_in[4];
  const float* b2     = (const float*)d_in[5];
  const float* Wl1    = (const float*)d_in[6];
  const float* bl1    = (const float*)d_in[7];
  const float* Wr1    = (const float*)d_in[8];
  const float* br1    = (const float*)d_in[9];
  const float* att1   = (const float*)d_in[10];
  const float* bias1  = (const float*)d_in[11];
  const float* Wl2    = (const float*)d_in[12];
  const float* bl2    = (const float*)d_in[13];
  const float* Wr2    = (const float*)d_in[14];
  const float* br2    = (const float*)d_in[15];
  const float* att2   = (const float*)d_in[16];
  const float* bias2  = (const float*)d_in[17];
  const float* ln_g   = (const float*)d_in[18];
  const float* ln_b   = (const float*)d_in[19];
  float* out = (float*)d_out;

  char* p = (char*)d_ws;
  _Float16* h0     = (_Float16*)p; p += (size_t)NN * 768 * 2;
  _Float16* h1     = (_Float16*)p; p += (size_t)NN * 512 * 2;
  _Float16* Wt1    = (_Float16*)p; p += (size_t)1024 * 768 * 2;
  _Float16* Wt2cat = (_Float16*)p; p += (size_t)512 * 512 * 2;
  _Float16* att_h  = (_Float16*)p; p += 1024;
  float* biasc     = (float*)p; p += 1024 * 4;
  _Float16* xl2    = (_Float16*)p; p += (size_t)NN * 256 * 2;

  prep_all<<<2560 + 1025, 256, 0, stream>>>(x, rel, w1, b1, w2, b2, Wl1, Wr1, Wl2, Wr2,
                                            bl1, br1, att1, h0, Wt1, Wt2cat, biasc, att_h);

  gemm1gat1<<<512, 512, 0, stream>>>(h0, Wt1, biasc, att_h, bias1, h1);

  gemm2a<<<640, 256, 0, stream>>>(h1, Wt2cat, bl2, xl2);

  gat2ln<<<BB, 512, 0, stream>>>(h1, xl2, Wt2cat, br2, att2, bias2, ln_g, ln_b, out);
}

// Round 11
// 181.231 us; speedup vs baseline: 1.0045x; 1.0045x over previous
//
#include <hip/hip_runtime.h>
#include <hip/hip_bf16.h>

#define NN 10240
#define LL 80
#define BB 128

typedef _Float16 half8 __attribute__((ext_vector_type(8)));
typedef _Float16 half2v __attribute__((ext_vector_type(2)));
typedef float f32x4 __attribute__((ext_vector_type(4)));

#define GLD16(gptr, lptr)                                                        \
  __builtin_amdgcn_global_load_lds(                                              \
      (const __attribute__((address_space(1))) void*)(gptr),                     \
      (__attribute__((address_space(3))) void*)(lptr), 16, 0, 0)

__device__ __forceinline__ float dot2f(half2v a, half2v b, float c) {
#if __has_builtin(__builtin_amdgcn_fdot2)
  return __builtin_amdgcn_fdot2(a, b, c, false);
#else
  return c + (float)a.x * (float)b.x + (float)a.y * (float)b.y;
#endif
}
__device__ __forceinline__ half2v u2h(unsigned int u) { half2v r; __builtin_memcpy(&r, &u, 4); return r; }
__device__ __forceinline__ unsigned int h2u(half2v h) { unsigned int u; __builtin_memcpy(&u, &h, 4); return u; }
// row offset (f16 units): 144B stride -> 16B-aligned rows (b128-legal)
__device__ __forceinline__ int roff(int r) { return r * 72; }

// 4 dwords (8 ch) of logit dot with pre-hoisted att regs: acc += att . lrelu(xl + xr)
__device__ __forceinline__ float dotq4r(uint4 a, uint4 b, const half2v* atv, int qb, float acc) {
  const half2v c02 = {(_Float16)0.2f, (_Float16)0.2f};
  unsigned int aa[4] = {a.x, a.y, a.z, a.w};
  unsigned int bb[4] = {b.x, b.y, b.z, b.w};
#pragma unroll
  for (int j = 0; j < 4; ++j) {
    half2v e = u2h(aa[j]) + u2h(bb[j]);
    half2v l = __builtin_elementwise_max(e, e * c02);
    acc = dot2f(l, atv[qb + j], acc);
  }
  return acc;
}

// ================= prep_all: gate_scale (4 nodes/block, vectorized) + transposes ================
__global__ __launch_bounds__(256) void prep_all(
    const float* __restrict__ x, const float* __restrict__ rel,
    const float* __restrict__ w1, const float* __restrict__ b1,
    const float* __restrict__ w2, const float* __restrict__ b2,
    const float* __restrict__ Wl1, const float* __restrict__ Wr1,
    const float* __restrict__ Wl2, const float* __restrict__ Wr2,
    const float* __restrict__ bl1, const float* __restrict__ br1,
    const float* __restrict__ att1,
    _Float16* __restrict__ h0, _Float16* __restrict__ Wt1,
    _Float16* __restrict__ Wt2cat,
    float* __restrict__ biasc, _Float16* __restrict__ att_h) {
  __shared__ float tile[32][33];
  int bid = blockIdx.x;
  int tid = threadIdx.x;
  if (bid < 2560) {
    int wave = tid >> 6, l = tid & 63;
    int n = bid * 4 + wave;
    float r0 = rel[n * 3 + 0], r1 = rel[n * 3 + 1], r2 = rel[n * 3 + 2];
    float v = r0 * w1[l] + r1 * w1[64 + l] + r2 * w1[128 + l] + b1[l];
    v = v > 0.f ? v : 0.f;
    v *= w2[l];
    for (int d = 32; d; d >>= 1) v += __shfl_down(v, d, 64);
    float s = __shfl(v, 0, 64);
    float g = 1.f / (1.f + __expf(-(s + b2[0])));
    const float4* xr = (const float4*)(x + (size_t)n * 768);
    _Float16* hr = h0 + (size_t)n * 768;
#pragma unroll
    for (int i = 0; i < 3; ++i) {
      int f = i * 64 + l;
      float4 xv = xr[f];
      half2v p0 = {(_Float16)(xv.x * g), (_Float16)(xv.y * g)};
      half2v p1 = {(_Float16)(xv.z * g), (_Float16)(xv.w * g)};
      uint2 ov = {h2u(p0), h2u(p1)};
      *(uint2*)&hr[f * 4] = ov;
    }
    return;
  }
  int r = bid - 2560;
  const float* W;
  _Float16* Wt;
  int K, Nc, bx, by;
  if (r < 384)      { W = Wl1; Wt = Wt1;                          K = 768; Nc = 512; bx = r % 16;       by = r / 16; }
  else if (r < 768) { W = Wr1; Wt = Wt1 + (size_t)512 * 768;      K = 768; Nc = 512; bx = (r-384) % 16; by = (r-384) / 16; }
  else if (r < 896) { W = Wl2; Wt = Wt2cat;                       K = 512; Nc = 256; bx = (r-768) % 8;  by = (r-768) / 8; }
  else if (r < 1024){ W = Wr2; Wt = Wt2cat + (size_t)256 * 512;   K = 512; Nc = 256; bx = (r-896) % 8;  by = (r-896) / 8; }
  else {
    for (int i = tid; i < 1024; i += 256) biasc[i] = (i < 512) ? bl1[i] : br1[i - 512];
    for (int i = tid; i < 512; i += 256) att_h[i] = (_Float16)att1[i];
    return;
  }
  int n0 = bx * 32, k0 = by * 32;
  int c = tid & 31, rr = tid >> 5;
#pragma unroll
  for (int p = 0; p < 4; ++p) {
    int rw = p * 8 + rr;
    tile[rw][c] = W[(size_t)(k0 + rw) * Nc + n0 + c];
  }
  __syncthreads();
#pragma unroll
  for (int p = 0; p < 4; ++p) {
    int rw = p * 8 + rr;
    Wt[(size_t)(n0 + rw) * K + k0 + c] = (_Float16)tile[c][rw];
  }
}

// ================= fused gemm1 + GATv2 layer-1 ================
// block = (head, dialogue): h = bx>>7, b = bx&127. grid 1024.
// GEMM: BK=32, 24 slabs, 2-phase double-buffered (STAGE next -> COMPUTE cur -> barrier),
//   staging 26KB -> total LDS 39936 -> 4 blocks/CU in ONE residency wave + drain-free
//   pipeline (R3 occupancy + R6 structure).
// NaN FIX (R9 post-mortem): phase-5 B-fragments read xlT K in [80,96) = the unwritten
//   88-stride pad + row-64 overflow. P is 0 there, but 0*Inf = NaN. In R3-R7 the pad
//   overlaid dead staging (finite); with 26KB staging it is raw LDS -> MUST be zeroed.
// GAT (unchanged): logits -> softmax -> dense alpha P[80][104] -> MFMA P@xlT -> ELU -> h1.
// LDS map: staging Ab 2x2560 f16 @0 (10240), Bb 2x4096 f16 @10240 (16384) -> 26624.
//   GAT overlay: xl@0 11520, xr@11520 11520, logit@23040 4160, src8@27200 1040,
//   hub@28240 320, xlT@28560 11264 -> 39824 <= 39936. P overlays @0 (16640).
__global__ __launch_bounds__(512, 8) void gemm1gat1(
    const _Float16* __restrict__ h0, const _Float16* __restrict__ Wt1,
    const float* __restrict__ biasc, const _Float16* __restrict__ att_h,
    const float* __restrict__ bias1, _Float16* __restrict__ h1) {
  __shared__ __align__(16) char smem[39936];
  _Float16* Ab = (_Float16*)smem;              // 2 x 2560 f16
  _Float16* Bb = (_Float16*)(smem + 10240);    // 2 x 4096 f16
  _Float16* s_xl = (_Float16*)smem;
  _Float16* s_xr = (_Float16*)(smem + 11520);
  float* s_logit = (float*)(smem + 23040);
  signed char* s_src8 = (signed char*)(smem + 27200);
  float* s_hub = (float*)(smem + 28240);
  _Float16* s_xlT = (_Float16*)(smem + 28560);
  _Float16* s_P = (_Float16*)smem;   // overlays xl+xr after logits

  int bx = blockIdx.x;
  int h = bx >> 7, b = bx & 127;
  int base = b * LL;
  int tid = threadIdx.x;
  int wave = tid >> 6, lane = tid & 63;
  int lr = lane & 15, lk = lane >> 4;

  // ---- NaN fix: zero xlT K-pad cols [80,88) of all 64 rows + the row-64 overflow
  //      slot [5632,5640) (read by kc=2,lk=3 of row 63). Disjoint from staging
  //      [0,26624); many barriers separate these writes from phase-5 reads.
  {
    int z = tid;                       // 520 elements, 512 threads: threads 0..7 do 2
    int rr2 = z >> 3, kk = z & 7;
    if (z < 512) s_xlT[rr2 * 88 + 80 + kk] = (_Float16)0.f;
    if (z < 8) s_xlT[64 * 88 + z] = (_Float16)0.f;   // 5632+z
  }

  // ---- staging pointers (proven gemm2a BK=32 pattern; seg = (lane&3)^((lane>>3)&3)) ----
  int seg8 = ((lane & 3) ^ ((lane >> 3) & 3)) * 8;
  const _Float16* aP = h0;
  if (wave < 5) {
    int c = wave * 64 + lane;                  // 0..319: row = c>>2
    aP = h0 + (size_t)(base + (c >> 2)) * 768 + seg8;
  }
  int cB = wave * 64 + lane;                   // 0..511: row = cB>>2 in [0,128)
  int brow = cB >> 2;
  int wrow = (brow < 64) ? (h * 64 + brow) : (512 + h * 64 + (brow - 64));
  const _Float16* bP = Wt1 + (size_t)wrow * 768 + seg8;
  int xk8 = (lk ^ ((lr >> 1) & 3)) * 8;

  f32x4 acc[5] = {};
  // prologue: stage tile 0 into buffer 0
  if (wave < 5) GLD16(aP, Ab + wave * 512);
  GLD16(bP, Bb + wave * 512);
  __syncthreads();
  for (int t = 0; t < 24; ++t) {
    int cur = t & 1;
    if (t < 23) {
      int k0 = (t + 1) * 32;
      int nb = cur ^ 1;
      if (wave < 5) GLD16(aP + k0, Ab + nb * 2560 + wave * 512);
      GLD16(bP + k0, Bb + nb * 4096 + wave * 512);
    }
    const _Float16* Ac = Ab + cur * 2560;
    const _Float16* Bc = Bb + cur * 4096;
    half8 bf = *(const half8*)(Bc + (wave * 16 + lr) * 32 + xk8);
#pragma unroll
    for (int m = 0; m < 5; ++m) {
      half8 af = *(const half8*)(Ac + (m * 16 + lr) * 32 + xk8);
      acc[m] = __builtin_amdgcn_mfma_f32_16x16x32_f16(af, bf, acc[m], 0, 0, 0);
    }
    __syncthreads();
  }
  // ---- epilogue: xl/xr (+bias) into LDS tiles (+ xlT k-major copy); adjacency build ----
  {
    int c = wave * 16 + lr;          // 0..127
    bool isxl = c < 64;
    int cc = isxl ? c : c - 64;
    float bb = biasc[(isxl ? 0 : 512) + h * 64 + cc];
    _Float16* dst = isxl ? s_xl : s_xr;
#pragma unroll
    for (int m = 0; m < 5; ++m)
#pragma unroll
      for (int rg = 0; rg < 4; ++rg) {
        int row = m * 16 + lk * 4 + rg;
        _Float16 hv = (_Float16)(acc[m][rg] + bb);
        dst[roff(row) + cc] = hv;
        if (isxl) s_xlT[cc * 88 + row] = hv;
      }
  }
  if (tid < 79) {
    int d = tid;
    signed char list[13];
    int c = 0;
    list[c++] = (signed char)d;
    if (d > 0) list[c++] = (signed char)(d - 1);
    if (d + 1 < 79) list[c++] = (signed char)(d + 1);
    list[c++] = 79;
    for (int j = d & 7; j < 80; j += 8)
      if (j != d && j != 79) list[c++] = (signed char)j;
    for (int i = c; i < 13; ++i) list[i] = -1;
#pragma unroll
    for (int i = 0; i < 13; ++i) s_src8[i * 80 + d] = list[i];
  }
  __syncthreads();

  // ---- edge logits: dst-grouped, att hoisted to SGPR, xr cached in regs, xl as b128 ----
  const unsigned int* pat = (const unsigned int*)(att_h + h * 64);
  half2v atv[32];
#pragma unroll
  for (int q = 0; q < 32; ++q) atv[q] = u2h(__builtin_amdgcn_readfirstlane(pat[q]));
  if (tid < 474) {
    int d = tid / 6, io = tid % 6;
    const uint4* pxr = (const uint4*)(s_xr + roff(d));
    uint4 xrr[8];
#pragma unroll
    for (int q = 0; q < 8; ++q) xrr[q] = pxr[q];
#pragma unroll
    for (int k = 0; k < 3; ++k) {
      int i = io + 6 * k;
      if (i < 13) {
        int src = s_src8[i * 80 + d];
        if (src < 0) {
          s_logit[i * 80 + d] = -3e38f;
        } else {
          const uint4* pxl = (const uint4*)(s_xl + roff(src));
          float a2 = 0.f;
#pragma unroll
          for (int q = 0; q < 8; ++q) a2 = dotq4r(pxl[q], xrr[q], atv, q * 4, a2);
          s_logit[i * 80 + d] = a2;
        }
      }
    }
  } else {
    int j = tid - 474;
    const uint4* pxr = (const uint4*)(s_xr + roff(79));
    uint4 xrr[8];
#pragma unroll
    for (int q = 0; q < 8; ++q) xrr[q] = pxr[q];
#pragma unroll
    for (int k = 0; k < 3; ++k) {
      int s = j + 38 * k;
      if (s < 80) {
        const uint4* pxl = (const uint4*)(s_xl + roff(s));
        float a2 = 0.f;
#pragma unroll
        for (int q = 0; q < 8; ++q) a2 = dotq4r(pxl[q], xrr[q], atv, q * 4, a2);
        s_hub[s] = a2;
      }
    }
  }
  __syncthreads();

  // ---- phase 3: zero dense P + compute alphas into regs ----
  {
    uint4 z4 = {0u, 0u, 0u, 0u};
    for (int z = tid; z < 1040; z += 512) ((uint4*)smem)[z] = z4;  // P [0,16640)
  }
  float va[13], inv_d = 0.f;
  bool isd = tid < 79;
  if (isd) {
    int d = tid;
    float m = -3e38f;
#pragma unroll
    for (int i = 0; i < 13; ++i) { va[i] = s_logit[i * 80 + d]; m = fmaxf(m, va[i]); }
    float sum = 0.f;
#pragma unroll
    for (int i = 0; i < 13; ++i) { va[i] = __expf(va[i] - m); sum += va[i]; }
    inv_d = 1.f / sum;
  }
  float he0 = 0.f, he1 = 0.f, hinv = 0.f;
  if (wave == 7) {
    int l = lane;
    float v0 = s_hub[l];
    float v1 = (l < 16) ? s_hub[64 + l] : -3e38f;
    float m = fmaxf(v0, v1);
    for (int d = 32; d; d >>= 1) m = fmaxf(m, __shfl_xor(m, d, 64));
    he0 = __expf(v0 - m);
    he1 = (l < 16) ? __expf(v1 - m) : 0.f;
    float sum = he0 + he1;
    for (int d = 32; d; d >>= 1) sum += __shfl_xor(sum, d, 64);
    hinv = 1.f / sum;
  }
  __syncthreads();

  // ---- phase 4: scatter alphas into P (f16) ----
  if (isd) {
    int d = tid;
#pragma unroll
    for (int i = 0; i < 13; ++i) {
      int src = s_src8[i * 80 + d];
      if (src >= 0) s_P[d * 104 + src] = (_Float16)(va[i] * inv_d);
    }
  }
  if (wave == 7) {
    int l = lane;
    s_P[79 * 104 + l] = (_Float16)(he0 * hinv);
    if (l < 16) s_P[79 * 104 + 64 + l] = (_Float16)(he1 * hinv);
  }
  __syncthreads();

  // ---- phase 5: MFMA aggregation out[80x64] = P[80x80(pad96)] @ xlT^T; ELU; h1 ----
  {
    int nt = (wave < 4) ? 3 : 2;
    int tb = (wave < 4) ? wave * 3 : 12 + (wave - 4) * 2;
    for (int tt = 0; tt < nt; ++tt) {
      int t = tb + tt;
      int m = t >> 2, n = t & 3;   // m 0..4, n 0..3
      f32x4 a = {};
#pragma unroll
      for (int kc = 0; kc < 3; ++kc) {
        half8 af = *(const half8*)(s_P + (m * 16 + lr) * 104 + kc * 32 + lk * 8);
        half8 bf = *(const half8*)(s_xlT + (n * 16 + lr) * 88 + kc * 32 + lk * 8);
        a = __builtin_amdgcn_mfma_f32_16x16x32_f16(af, bf, a, 0, 0, 0);
      }
      int c = n * 16 + lr;
      float bb = bias1[h * 64 + c];
#pragma unroll
      for (int rg = 0; rg < 4; ++rg) {
        int d = m * 16 + lk * 4 + rg;   // < 80
        float v = a[rg] + bb;
        v = v > 0.f ? v : __expf(v) - 1.f;
        h1[(size_t)(base + d) * 512 + h * 64 + c] = (_Float16)v;
      }
    }
  }
}

// ================= gemm2a: xl2 = h1 @ Wl2 + bl2 (unchanged from R7) ==============
__global__ __launch_bounds__(256) void gemm2a(
    const _Float16* __restrict__ h1, const _Float16* __restrict__ Bt,
    const float* __restrict__ bl2, _Float16* __restrict__ xl2) {
  __shared__ __align__(16) char smem[16384];
  _Float16* Ab = (_Float16*)smem;            // 2 x 2048 f16
  _Float16* Bb = (_Float16*)(smem + 8192);   // 2 x 2048 f16
  int bx = blockIdx.x;
  int mb = bx >> 2, nb = bx & 3;
  int tid = threadIdx.x;
  int wave = tid >> 6, lane = tid & 63;
  int lr = lane & 15, lk = lane >> 4;
  int seg8 = ((lane & 3) ^ ((lane >> 3) & 3)) * 8;
  int row = tid >> 2;               // 0..63
  const _Float16* aP = h1 + (size_t)(mb * 64 + row) * 512 + seg8;
  const _Float16* bP = Bt + (size_t)(nb * 64 + row) * 512 + seg8;
  int xk8 = (lk ^ ((lr >> 1) & 3)) * 8;
  f32x4 acc[4] = {};
  GLD16(aP, Ab + wave * 512);
  GLD16(bP, Bb + wave * 512);
  __syncthreads();
  for (int t = 0; t < 16; ++t) {
    int cur = t & 1;
    if (t < 15) {
      int k0 = (t + 1) * 32;
      int nbuf = cur ^ 1;
      GLD16(aP + k0, Ab + nbuf * 2048 + wave * 512);
      GLD16(bP + k0, Bb + nbuf * 2048 + wave * 512);
    }
    const _Float16* Ac = Ab + cur * 2048;
    const _Float16* Bc = Bb + cur * 2048;
    half8 bf = *(const half8*)(Bc + (wave * 16 + lr) * 32 + xk8);
#pragma unroll
    for (int m = 0; m < 4; ++m) {
      half8 af = *(const half8*)(Ac + (m * 16 + lr) * 32 + xk8);
      acc[m] = __builtin_amdgcn_mfma_f32_16x16x32_f16(af, bf, acc[m], 0, 0, 0);
    }
    __syncthreads();
  }
  int col = nb * 64 + wave * 16 + lr;
  float bb = bl2[col];
#pragma unroll
  for (int m = 0; m < 4; ++m)
#pragma unroll
    for (int rg = 0; rg < 4; ++rg) {
      int r = mb * 64 + m * 16 + lk * 4 + rg;
      xl2[(size_t)r * 256 + col] = (_Float16)(acc[m][rg] + bb);
    }
}

// ================= gat2ln: per-dialogue attention + LN (unchanged from R7) ==============
#define PX 264
__global__ __launch_bounds__(512) void gat2ln(
    const _Float16* __restrict__ h1, const _Float16* __restrict__ xl2,
    const _Float16* __restrict__ Bt, const float* __restrict__ br2,
    const float* __restrict__ att2, const float* __restrict__ bias2,
    const float* __restrict__ ln_g, const float* __restrict__ ln_b,
    float* __restrict__ out) {
  __shared__ __align__(16) _Float16 s_x[80 * PX];   // 42240 B
  __shared__ _Float16 s_att[256];
  __shared__ _Float16 s_xr[256];
  __shared__ float s_red[80];
  __shared__ float s_sum[4], s_sq[4];

  int b = blockIdx.x;
  int tid = threadIdx.x;
  int wave = tid >> 6, lane = tid & 63;

  if (tid < 256) s_att[tid] = (_Float16)att2[tid];
  // stage xl2[b] (80x256 f16) into s_x [80][PX] via b128
  for (int t = tid; t < 2560; t += 512) {
    int row = t >> 5, q = t & 31;
    uint4 v = *(const uint4*)(xl2 + ((size_t)(b * 80 + row)) * 256 + q * 8);
    *(uint4*)(s_x + row * PX + q * 8) = v;
  }
  // xr row 79: c = tid>>1, k-half = tid&1; global dots on Bt rows 256+c (L2-hot)
  {
    int c = tid >> 1, kh = tid & 1;
    const uint4* wr = (const uint4*)(Bt + (size_t)(256 + c) * 512 + kh * 256);
    const uint4* hq = (const uint4*)(h1 + (size_t)(b * 80 + 79) * 512 + kh * 256);
    float s = 0.f;
#pragma unroll 8
    for (int q = 0; q < 32; ++q) {
      uint4 ua = hq[q], uw = wr[q];
      s = dot2f(u2h(ua.x), u2h(uw.x), s);
      s = dot2f(u2h(ua.y), u2h(uw.y), s);
      s = dot2f(u2h(ua.z), u2h(uw.z), s);
      s = dot2f(u2h(ua.w), u2h(uw.w), s);
    }
    s += __shfl_xor(s, 1, 64);
    if (kh == 0) s_xr[c] = (_Float16)(s + br2[c]);
  }
  __syncthreads();
  if (tid < 160) {
    int r = tid >> 1, hf = tid & 1;
    const half2v* xa = (const half2v*)(s_x + r * PX + hf * 128);
    const half2v* xr = (const half2v*)(s_xr + hf * 128);
    const half2v* at = (const half2v*)(s_att + hf * 128);
    float lg = 0.f;
    const half2v c02 = {(_Float16)0.2f, (_Float16)0.2f};
#pragma unroll
    for (int q = 0; q < 64; ++q) {
      half2v e = xa[q] + xr[q];
      half2v l = __builtin_elementwise_max(e, e * c02);
      lg = dot2f(l, at[q], lg);
    }
    lg += __shfl_xor(lg, 1, 64);
    if (hf == 0) s_red[r] = lg;
  }
  __syncthreads();
  if (wave == 7) {
    float v0 = s_red[lane];
    float v1 = (lane < 16) ? s_red[64 + lane] : -3e38f;
    float m = fmaxf(v0, v1);
    for (int d = 32; d; d >>= 1) m = fmaxf(m, __shfl_xor(m, d, 64));
    float e0 = __expf(v0 - m);
    float e1 = (lane < 16) ? __expf(v1 - m) : 0.f;
    float sum = e0 + e1;
    for (int d = 32; d; d >>= 1) sum += __shfl_xor(sum, d, 64);
    float inv = 1.f / sum;
    s_red[lane] = e0 * inv;
    if (lane < 16) s_red[64 + lane] = e1 * inv;
  }
  __syncthreads();
  float v = 0.f;
  if (tid < 256) {
    float a = 0.f;
#pragma unroll
    for (int r = 0; r < 80; ++r) a += s_red[r] * (float)s_x[r * PX + tid];
    v = a + bias2[tid];
    float p = v;
    for (int d = 32; d; d >>= 1) p += __shfl_down(p, d, 64);
    if (lane == 0) s_sum[wave] = p;
    float q = v * v;
    for (int d = 32; d; d >>= 1) q += __shfl_down(q, d, 64);
    if (lane == 0) s_sq[wave] = q;
  }
  __syncthreads();
  if (tid < 256) {
    float mu = (s_sum[0] + s_sum[1] + s_sum[2] + s_sum[3]) * (1.f / 256.f);
    float ex2 = (s_sq[0] + s_sq[1] + s_sq[2] + s_sq[3]) * (1.f / 256.f);
    float var = ex2 - mu * mu;
    float r = rsqrtf(var + 1e-5f);
    out[b * 256 + tid] = (v - mu) * r * ln_g[tid] + ln_b[tid];
  }
}

extern "C" void kernel_launch(void* const* d_in, const int* in_sizes, int n_in,
                              void* d_out, int out_size, void* d_ws, size_t ws_size,
                              hipStream_t stream) {
  const float* x      = (const float*)d_in[0];
  const float* rel    = (const float*)d_in[1];
  const float* w1     = (const float*)d_in[2];
  const float* b1     = (const float*)d_in[3];
  const float* w2     = (const float*)d_in[4];
  const float* b2     = (const float*)d_in[5];
  const float* Wl1    = (const float*)d_in[6];
  const float* bl1    = (const float*)d_in[7];
  const float* Wr1    = (const float*)d_in[8];
  const float* br1    = (const float*)d_in[9];
  const float* att1   = (const float*)d_in[10];
  const float* bias1  = (const float*)d_in[11];
  const float* Wl2    = (const float*)d_in[12];
  const float* bl2    = (const float*)d_in[13];
  const float* Wr2    = (const float*)d_in[14];
  const float* br2    = (const float*)d_in[15];
  const float* att2   = (const float*)d_in[16];
  const float* bias2  = (const float*)d_in[17];
  const float* ln_g   = (const float*)d_in[18];
  const float* ln_b   = (const float*)d_in[19];
  float* out = (float*)d_out;

  char* p = (char*)d_ws;
  _Float16* h0     = (_Float16*)p; p += (size_t)NN * 768 * 2;
  _Float16* h1     = (_Float16*)p; p += (size_t)NN * 512 * 2;
  _Float16* Wt1    = (_Float16*)p; p += (size_t)1024 * 768 * 2;
  _Float16* Wt2cat = (_Float16*)p; p += (size_t)512 * 512 * 2;
  _Float16* att_h  = (_Float16*)p; p += 1024;
  float* biasc     = (float*)p; p += 1024 * 4;
  _Float16* xl2    = (_Float16*)p; p += (size_t)NN * 256 * 2;

  prep_all<<<2560 + 1025, 256, 0, stream>>>(x, rel, w1, b1, w2, b2, Wl1, Wr1, Wl2, Wr2,
                                            bl1, br1, att1, h0, Wt1, Wt2cat, biasc, att_h);

  gemm1gat1<<<1024, 512, 0, stream>>>(h0, Wt1, biasc, att_h, bias1, h1);

  gemm2a<<<640, 256, 0, stream>>>(h1, Wt2cat, bl2, xl2);

  gat2ln<<<BB, 512, 0, stream>>>(h1, xl2, Wt2cat, br2, att2, bias2, ln_g, ln_b, out);
}

// Round 12
// 168.187 us; speedup vs baseline: 1.0824x; 1.0776x over previous
//
#include <hip/hip_runtime.h>
#include <hip/hip_bf16.h>

#define NN 10240
#define LL 80
#define BB 128

typedef _Float16 half8 __attribute__((ext_vector_type(8)));
typedef _Float16 half2v __attribute__((ext_vector_type(2)));
typedef float f32x4 __attribute__((ext_vector_type(4)));

#define GLD16(gptr, lptr)                                                        \
  __builtin_amdgcn_global_load_lds(                                              \
      (const __attribute__((address_space(1))) void*)(gptr),                     \
      (__attribute__((address_space(3))) void*)(lptr), 16, 0, 0)

__device__ __forceinline__ float dot2f(half2v a, half2v b, float c) {
#if __has_builtin(__builtin_amdgcn_fdot2)
  return __builtin_amdgcn_fdot2(a, b, c, false);
#else
  return c + (float)a.x * (float)b.x + (float)a.y * (float)b.y;
#endif
}
__device__ __forceinline__ half2v u2h(unsigned int u) { half2v r; __builtin_memcpy(&r, &u, 4); return r; }
__device__ __forceinline__ unsigned int h2u(half2v h) { unsigned int u; __builtin_memcpy(&u, &h, 4); return u; }
// row offset (f16 units): 144B stride -> 16B-aligned rows (b128-legal)
__device__ __forceinline__ int roff(int r) { return r * 72; }

// 4 dwords (8 ch) of logit dot with pre-hoisted att regs: acc += att . lrelu(xl + xr)
__device__ __forceinline__ float dotq4r(uint4 a, uint4 b, const half2v* atv, int qb, float acc) {
  const half2v c02 = {(_Float16)0.2f, (_Float16)0.2f};
  unsigned int aa[4] = {a.x, a.y, a.z, a.w};
  unsigned int bb[4] = {b.x, b.y, b.z, b.w};
#pragma unroll
  for (int j = 0; j < 4; ++j) {
    half2v e = u2h(aa[j]) + u2h(bb[j]);
    half2v l = __builtin_elementwise_max(e, e * c02);
    acc = dot2f(l, atv[qb + j], acc);
  }
  return acc;
}

// ================= prep_all: gate_scale (4 nodes/block, vectorized) + transposes ================
__global__ __launch_bounds__(256) void prep_all(
    const float* __restrict__ x, const float* __restrict__ rel,
    const float* __restrict__ w1, const float* __restrict__ b1,
    const float* __restrict__ w2, const float* __restrict__ b2,
    const float* __restrict__ Wl1, const float* __restrict__ Wr1,
    const float* __restrict__ Wl2, const float* __restrict__ Wr2,
    const float* __restrict__ bl1, const float* __restrict__ br1,
    const float* __restrict__ att1,
    _Float16* __restrict__ h0, _Float16* __restrict__ Wt1,
    _Float16* __restrict__ Wt2cat,
    float* __restrict__ biasc, _Float16* __restrict__ att_h) {
  __shared__ float tile[32][33];
  int bid = blockIdx.x;
  int tid = threadIdx.x;
  if (bid < 2560) {
    int wave = tid >> 6, l = tid & 63;
    int n = bid * 4 + wave;
    float r0 = rel[n * 3 + 0], r1 = rel[n * 3 + 1], r2 = rel[n * 3 + 2];
    float v = r0 * w1[l] + r1 * w1[64 + l] + r2 * w1[128 + l] + b1[l];
    v = v > 0.f ? v : 0.f;
    v *= w2[l];
    for (int d = 32; d; d >>= 1) v += __shfl_down(v, d, 64);
    float s = __shfl(v, 0, 64);
    float g = 1.f / (1.f + __expf(-(s + b2[0])));
    const float4* xr = (const float4*)(x + (size_t)n * 768);
    _Float16* hr = h0 + (size_t)n * 768;
#pragma unroll
    for (int i = 0; i < 3; ++i) {
      int f = i * 64 + l;
      float4 xv = xr[f];
      half2v p0 = {(_Float16)(xv.x * g), (_Float16)(xv.y * g)};
      half2v p1 = {(_Float16)(xv.z * g), (_Float16)(xv.w * g)};
      uint2 ov = {h2u(p0), h2u(p1)};
      *(uint2*)&hr[f * 4] = ov;
    }
    return;
  }
  int r = bid - 2560;
  const float* W;
  _Float16* Wt;
  int K, Nc, bx, by;
  if (r < 384)      { W = Wl1; Wt = Wt1;                          K = 768; Nc = 512; bx = r % 16;       by = r / 16; }
  else if (r < 768) { W = Wr1; Wt = Wt1 + (size_t)512 * 768;      K = 768; Nc = 512; bx = (r-384) % 16; by = (r-384) / 16; }
  else if (r < 896) { W = Wl2; Wt = Wt2cat;                       K = 512; Nc = 256; bx = (r-768) % 8;  by = (r-768) / 8; }
  else if (r < 1024){ W = Wr2; Wt = Wt2cat + (size_t)256 * 512;   K = 512; Nc = 256; bx = (r-896) % 8;  by = (r-896) / 8; }
  else {
    for (int i = tid; i < 1024; i += 256) biasc[i] = (i < 512) ? bl1[i] : br1[i - 512];
    for (int i = tid; i < 512; i += 256) att_h[i] = (_Float16)att1[i];
    return;
  }
  int n0 = bx * 32, k0 = by * 32;
  int c = tid & 31, rr = tid >> 5;
#pragma unroll
  for (int p = 0; p < 4; ++p) {
    int rw = p * 8 + rr;
    tile[rw][c] = W[(size_t)(k0 + rw) * Nc + n0 + c];
  }
  __syncthreads();
#pragma unroll
  for (int p = 0; p < 4; ++p) {
    int rw = p * 8 + rr;
    Wt[(size_t)(n0 + rw) * K + k0 + c] = (_Float16)tile[c][rw];
  }
}

// ================= fused gemm1 + GATv2 layer-1 (R6 structure — best measured, ~41 us) ========
// block = (head, dialogue): h = bx>>7, b = bx&127.
// GEMM: 2-phase double-buffered, BK=64, 12 tiles, ONE barrier per tile (barrier count is
//   the measured wall: 12 barriers ~41us < 16 ~41.7 < 24 ~44.8; R11 falsified the
//   residency model). LDS 53248 -> 3 blocks/CU. All 8 waves compute.
//   Swizzle: src seg=(lane&7)^((lane>>3)&7), read slot=(s2*4+lk)^(lr&7).
// NaN-safety note (R9 lesson): xlT's 88-stride K-pad [80,88) is read by phase-5 with
//   P=0; here xlT (28560..39824) fully overlays Bb staging (10240..43008) which is
//   completely written with finite f16 each slab -> 0 x finite = 0. Deterministic.
// GAT: logits -> softmax -> dense alpha P[80][104] -> MFMA P@xlT -> ELU -> h1.
// LDS map: staging Ab 2x5120 @0 (20480), Bb 2x8192 @20480 (32768) -> 53248.
//   GAT overlay: xl@0 11520, xr@11520 11520, logit@23040 4160, src8@27200 1040,
//   hub@28240 320, xlT@28560 11264 -> 39824; P overlays @0 (16640).
__global__ __launch_bounds__(512, 6) void gemm1gat1(
    const _Float16* __restrict__ h0, const _Float16* __restrict__ Wt1,
    const float* __restrict__ biasc, const _Float16* __restrict__ att_h,
    const float* __restrict__ bias1, _Float16* __restrict__ h1) {
  __shared__ __align__(16) char smem[53248];
  _Float16* Ab = (_Float16*)smem;              // 2 x 5120 f16
  _Float16* Bb = (_Float16*)(smem + 20480);    // 2 x 8192 f16
  _Float16* s_xl = (_Float16*)smem;
  _Float16* s_xr = (_Float16*)(smem + 11520);
  float* s_logit = (float*)(smem + 23040);
  signed char* s_src8 = (signed char*)(smem + 27200);
  float* s_hub = (float*)(smem + 28240);
  _Float16* s_xlT = (_Float16*)(smem + 28560);
  _Float16* s_P = (_Float16*)smem;   // overlays xl+xr after logits

  int bx = blockIdx.x;
  int h = bx >> 7, b = bx & 127;
  int base = b * LL;
  int tid = threadIdx.x;
  int wave = tid >> 6, lane = tid & 63;
  int lr = lane & 15, lk = lane >> 4;

  // ---- staging pointers: source pre-swizzled, seg = (lane&7)^((lane>>3)&7) ----
  int segA8 = ((lane & 7) ^ ((lane >> 3) & 7)) * 8;
  int r0a = wave * 16 + (lane >> 3);          // j=0 row
  const _Float16* aP0 = h0;
  const _Float16* aP1 = h0;
  if (wave < 5) {                              // A rows 0..79
    aP0 = h0 + (size_t)(base + r0a) * 768 + segA8;
    aP1 = h0 + (size_t)(base + r0a + 8) * 768 + segA8;
  }
  int rb0 = r0a, rb1 = r0a + 8;                // B rows 0..127
  int wr0 = (rb0 < 64) ? (h * 64 + rb0) : (512 + h * 64 + (rb0 - 64));
  int wr1 = (rb1 < 64) ? (h * 64 + rb1) : (512 + h * 64 + (rb1 - 64));
  const _Float16* bP0 = Wt1 + (size_t)wr0 * 768 + segA8;
  const _Float16* bP1 = Wt1 + (size_t)wr1 * 768 + segA8;

  f32x4 acc[5] = {};
  // prologue: stage tile 0 into buffer 0
  if (wave < 5) {
    GLD16(aP0, Ab + wave * 1024);
    GLD16(aP1, Ab + wave * 1024 + 512);
  }
  GLD16(bP0, Bb + wave * 1024);
  GLD16(bP1, Bb + wave * 1024 + 512);
  __syncthreads();
  for (int t = 0; t < 12; ++t) {
    int cur = t & 1;
    if (t < 11) {
      int k0 = (t + 1) * 64;
      int nb = cur ^ 1;
      if (wave < 5) {
        GLD16(aP0 + k0, Ab + nb * 5120 + wave * 1024);
        GLD16(aP1 + k0, Ab + nb * 5120 + wave * 1024 + 512);
      }
      GLD16(bP0 + k0, Bb + nb * 8192 + wave * 1024);
      GLD16(bP1 + k0, Bb + nb * 8192 + wave * 1024 + 512);
    }
    const _Float16* Ac = Ab + cur * 5120;
    const _Float16* Bc = Bb + cur * 8192;
    int rB = wave * 16 + lr;
#pragma unroll
    for (int s2 = 0; s2 < 2; ++s2) {
      int cx = ((s2 * 4 + lk) ^ (lr & 7)) * 8;
      half8 bf = *(const half8*)(Bc + rB * 64 + cx);
#pragma unroll
      for (int m = 0; m < 5; ++m) {
        half8 af = *(const half8*)(Ac + (m * 16 + lr) * 64 + cx);
        acc[m] = __builtin_amdgcn_mfma_f32_16x16x32_f16(af, bf, acc[m], 0, 0, 0);
      }
    }
    __syncthreads();
  }
  // ---- epilogue: xl/xr (+bias) into LDS tiles (+ xlT k-major copy); adjacency build ----
  {
    int c = wave * 16 + lr;          // 0..127
    bool isxl = c < 64;
    int cc = isxl ? c : c - 64;
    float bb = biasc[(isxl ? 0 : 512) + h * 64 + cc];
    _Float16* dst = isxl ? s_xl : s_xr;
#pragma unroll
    for (int m = 0; m < 5; ++m)
#pragma unroll
      for (int rg = 0; rg < 4; ++rg) {
        int row = m * 16 + lk * 4 + rg;
        _Float16 hv = (_Float16)(acc[m][rg] + bb);
        dst[roff(row) + cc] = hv;
        if (isxl) s_xlT[cc * 88 + row] = hv;
      }
  }
  if (tid < 79) {
    int d = tid;
    signed char list[13];
    int c = 0;
    list[c++] = (signed char)d;
    if (d > 0) list[c++] = (signed char)(d - 1);
    if (d + 1 < 79) list[c++] = (signed char)(d + 1);
    list[c++] = 79;
    for (int j = d & 7; j < 80; j += 8)
      if (j != d && j != 79) list[c++] = (signed char)j;
    for (int i = c; i < 13; ++i) list[i] = -1;
#pragma unroll
    for (int i = 0; i < 13; ++i) s_src8[i * 80 + d] = list[i];
  }
  __syncthreads();

  // ---- edge logits: dst-grouped, att hoisted to SGPR, xr cached in regs, xl as b128 ----
  const unsigned int* pat = (const unsigned int*)(att_h + h * 64);
  half2v atv[32];
#pragma unroll
  for (int q = 0; q < 32; ++q) atv[q] = u2h(__builtin_amdgcn_readfirstlane(pat[q]));
  if (tid < 474) {
    int d = tid / 6, io = tid % 6;
    const uint4* pxr = (const uint4*)(s_xr + roff(d));
    uint4 xrr[8];
#pragma unroll
    for (int q = 0; q < 8; ++q) xrr[q] = pxr[q];
#pragma unroll
    for (int k = 0; k < 3; ++k) {
      int i = io + 6 * k;
      if (i < 13) {
        int src = s_src8[i * 80 + d];
        if (src < 0) {
          s_logit[i * 80 + d] = -3e38f;
        } else {
          const uint4* pxl = (const uint4*)(s_xl + roff(src));
          float a2 = 0.f;
#pragma unroll
          for (int q = 0; q < 8; ++q) a2 = dotq4r(pxl[q], xrr[q], atv, q * 4, a2);
          s_logit[i * 80 + d] = a2;
        }
      }
    }
  } else {
    int j = tid - 474;
    const uint4* pxr = (const uint4*)(s_xr + roff(79));
    uint4 xrr[8];
#pragma unroll
    for (int q = 0; q < 8; ++q) xrr[q] = pxr[q];
#pragma unroll
    for (int k = 0; k < 3; ++k) {
      int s = j + 38 * k;
      if (s < 80) {
        const uint4* pxl = (const uint4*)(s_xl + roff(s));
        float a2 = 0.f;
#pragma unroll
        for (int q = 0; q < 8; ++q) a2 = dotq4r(pxl[q], xrr[q], atv, q * 4, a2);
        s_hub[s] = a2;
      }
    }
  }
  __syncthreads();

  // ---- phase 3: zero dense P + compute alphas into regs ----
  {
    uint4 z4 = {0u, 0u, 0u, 0u};
    for (int z = tid; z < 1040; z += 512) ((uint4*)smem)[z] = z4;  // P [0,16640)
  }
  float va[13], inv_d = 0.f;
  bool isd = tid < 79;
  if (isd) {
    int d = tid;
    float m = -3e38f;
#pragma unroll
    for (int i = 0; i < 13; ++i) { va[i] = s_logit[i * 80 + d]; m = fmaxf(m, va[i]); }
    float sum = 0.f;
#pragma unroll
    for (int i = 0; i < 13; ++i) { va[i] = __expf(va[i] - m); sum += va[i]; }
    inv_d = 1.f / sum;
  }
  float he0 = 0.f, he1 = 0.f, hinv = 0.f;
  if (wave == 7) {
    int l = lane;
    float v0 = s_hub[l];
    float v1 = (l < 16) ? s_hub[64 + l] : -3e38f;
    float m = fmaxf(v0, v1);
    for (int d = 32; d; d >>= 1) m = fmaxf(m, __shfl_xor(m, d, 64));
    he0 = __expf(v0 - m);
    he1 = (l < 16) ? __expf(v1 - m) : 0.f;
    float sum = he0 + he1;
    for (int d = 32; d; d >>= 1) sum += __shfl_xor(sum, d, 64);
    hinv = 1.f / sum;
  }
  __syncthreads();

  // ---- phase 4: scatter alphas into P (f16) ----
  if (isd) {
    int d = tid;
#pragma unroll
    for (int i = 0; i < 13; ++i) {
      int src = s_src8[i * 80 + d];
      if (src >= 0) s_P[d * 104 + src] = (_Float16)(va[i] * inv_d);
    }
  }
  if (wave == 7) {
    int l = lane;
    s_P[79 * 104 + l] = (_Float16)(he0 * hinv);
    if (l < 16) s_P[79 * 104 + 64 + l] = (_Float16)(he1 * hinv);
  }
  __syncthreads();

  // ---- phase 5: MFMA aggregation out[80x64] = P[80x80(pad96)] @ xlT^T; ELU; h1 ----
  {
    int nt = (wave < 4) ? 3 : 2;
    int tb = (wave < 4) ? wave * 3 : 12 + (wave - 4) * 2;
    for (int tt = 0; tt < nt; ++tt) {
      int t = tb + tt;
      int m = t >> 2, n = t & 3;   // m 0..4, n 0..3
      f32x4 a = {};
#pragma unroll
      for (int kc = 0; kc < 3; ++kc) {
        half8 af = *(const half8*)(s_P + (m * 16 + lr) * 104 + kc * 32 + lk * 8);
        half8 bf = *(const half8*)(s_xlT + (n * 16 + lr) * 88 + kc * 32 + lk * 8);
        a = __builtin_amdgcn_mfma_f32_16x16x32_f16(af, bf, a, 0, 0, 0);
      }
      int c = n * 16 + lr;
      float bb = bias1[h * 64 + c];
#pragma unroll
      for (int rg = 0; rg < 4; ++rg) {
        int d = m * 16 + lk * 4 + rg;   // < 80
        float v = a[rg] + bb;
        v = v > 0.f ? v : __expf(v) - 1.f;
        h1[(size_t)(base + d) * 512 + h * 64 + c] = (_Float16)v;
      }
    }
  }
}

// ================= gemm2a: xl2 = h1@Wl2+bl2 (640 blocks) AND xr2 = h1[last]@Wr2+br2 (8 blocks)
// Blocks 640..647 fold gat2ln's per-block 256KB Wr2 re-read into 8 tiles of the same
// 64x64 GEMM: A-rows gathered at node d*80+79, B-rows = Wt2cat rows 256.. (Wr2^T).
__global__ __launch_bounds__(256) void gemm2a(
    const _Float16* __restrict__ h1, const _Float16* __restrict__ Bt,
    const float* __restrict__ bl2, const float* __restrict__ br2,
    _Float16* __restrict__ xl2, _Float16* __restrict__ xr2) {
  __shared__ __align__(16) char smem[16384];
  _Float16* Ab = (_Float16*)smem;            // 2 x 2048 f16
  _Float16* Bb = (_Float16*)(smem + 8192);   // 2 x 2048 f16
  int bx = blockIdx.x;
  bool isxr = bx >= 640;
  int bl = isxr ? bx - 640 : bx;
  int mb = bl >> 2, nb = bl & 3;
  int tid = threadIdx.x;
  int wave = tid >> 6, lane = tid & 63;
  int lr = lane & 15, lk = lane >> 4;
  int seg8 = ((lane & 3) ^ ((lane >> 3) & 3)) * 8;
  int row = tid >> 2;               // 0..63
  size_t arow = isxr ? ((size_t)(mb * 64 + row) * 80 + 79) : (size_t)(mb * 64 + row);
  const _Float16* aP = h1 + arow * 512 + seg8;
  const _Float16* bP = Bt + (size_t)((isxr ? 256 : 0) + nb * 64 + row) * 512 + seg8;
  int xk8 = (lk ^ ((lr >> 1) & 3)) * 8;
  f32x4 acc[4] = {};
  GLD16(aP, Ab + wave * 512);
  GLD16(bP, Bb + wave * 512);
  __syncthreads();
  for (int t = 0; t < 16; ++t) {
    int cur = t & 1;
    if (t < 15) {
      int k0 = (t + 1) * 32;
      int nbuf = cur ^ 1;
      GLD16(aP + k0, Ab + nbuf * 2048 + wave * 512);
      GLD16(bP + k0, Bb + nbuf * 2048 + wave * 512);
    }
    const _Float16* Ac = Ab + cur * 2048;
    const _Float16* Bc = Bb + cur * 2048;
    half8 bf = *(const half8*)(Bc + (wave * 16 + lr) * 32 + xk8);
#pragma unroll
    for (int m = 0; m < 4; ++m) {
      half8 af = *(const half8*)(Ac + (m * 16 + lr) * 32 + xk8);
      acc[m] = __builtin_amdgcn_mfma_f32_16x16x32_f16(af, bf, acc[m], 0, 0, 0);
    }
    __syncthreads();
  }
  int col = nb * 64 + wave * 16 + lr;
  float bb = isxr ? br2[col] : bl2[col];
  _Float16* dst = isxr ? xr2 : xl2;
#pragma unroll
  for (int m = 0; m < 4; ++m)
#pragma unroll
    for (int rg = 0; rg < 4; ++rg) {
      int r = mb * 64 + m * 16 + lk * 4 + rg;
      dst[(size_t)r * 256 + col] = (_Float16)(acc[m][rg] + bb);
    }
}

// ================= gat2ln: per-dialogue attention + LN (xr now precomputed in gemm2a) ========
#define PX 264
__global__ __launch_bounds__(512) void gat2ln(
    const _Float16* __restrict__ xl2, const _Float16* __restrict__ xr2,
    const float* __restrict__ att2, const float* __restrict__ bias2,
    const float* __restrict__ ln_g, const float* __restrict__ ln_b,
    float* __restrict__ out) {
  __shared__ __align__(16) _Float16 s_x[80 * PX];   // 42240 B
  __shared__ _Float16 s_att[256];
  __shared__ _Float16 s_xr[256];
  __shared__ float s_red[80];
  __shared__ float s_sum[4], s_sq[4];

  int b = blockIdx.x;
  int tid = threadIdx.x;
  int wave = tid >> 6, lane = tid & 63;

  if (tid < 256) s_att[tid] = (_Float16)att2[tid];
  if (tid >= 256 && tid < 512 - 0) { /* spread LDS fill below */ }
  // stage xl2[b] (80x256 f16) into s_x [80][PX] via b128
  for (int t = tid; t < 2560; t += 512) {
    int row = t >> 5, q = t & 31;
    uint4 v = *(const uint4*)(xl2 + ((size_t)(b * 80 + row)) * 256 + q * 8);
    *(uint4*)(s_x + row * PX + q * 8) = v;
  }
  // xr row: precomputed by gemm2a's xr blocks — 512B coalesced load
  if (tid < 256) s_xr[tid] = xr2[(size_t)b * 256 + tid];
  __syncthreads();
  if (tid < 160) {
    int r = tid >> 1, hf = tid & 1;
    const half2v* xa = (const half2v*)(s_x + r * PX + hf * 128);
    const half2v* xr = (const half2v*)(s_xr + hf * 128);
    const half2v* at = (const half2v*)(s_att + hf * 128);
    float lg = 0.f;
    const half2v c02 = {(_Float16)0.2f, (_Float16)0.2f};
#pragma unroll
    for (int q = 0; q < 64; ++q) {
      half2v e = xa[q] + xr[q];
      half2v l = __builtin_elementwise_max(e, e * c02);
      lg = dot2f(l, at[q], lg);
    }
    lg += __shfl_xor(lg, 1, 64);
    if (hf == 0) s_red[r] = lg;
  }
  __syncthreads();
  if (wave == 7) {
    float v0 = s_red[lane];
    float v1 = (lane < 16) ? s_red[64 + lane] : -3e38f;
    float m = fmaxf(v0, v1);
    for (int d = 32; d; d >>= 1) m = fmaxf(m, __shfl_xor(m, d, 64));
    float e0 = __expf(v0 - m);
    float e1 = (lane < 16) ? __expf(v1 - m) : 0.f;
    float sum = e0 + e1;
    for (int d = 32; d; d >>= 1) sum += __shfl_xor(sum, d, 64);
    float inv = 1.f / sum;
    s_red[lane] = e0 * inv;
    if (lane < 16) s_red[64 + lane] = e1 * inv;
  }
  __syncthreads();
  float v = 0.f;
  if (tid < 256) {
    float a = 0.f;
#pragma unroll
    for (int r = 0; r < 80; ++r) a += s_red[r] * (float)s_x[r * PX + tid];
    v = a + bias2[tid];
    float p = v;
    for (int d = 32; d; d >>= 1) p += __shfl_down(p, d, 64);
    if (lane == 0) s_sum[wave] = p;
    float q = v * v;
    for (int d = 32; d; d >>= 1) q += __shfl_down(q, d, 64);
    if (lane == 0) s_sq[wave] = q;
  }
  __syncthreads();
  if (tid < 256) {
    float mu = (s_sum[0] + s_sum[1] + s_sum[2] + s_sum[3]) * (1.f / 256.f);
    float ex2 = (s_sq[0] + s_sq[1] + s_sq[2] + s_sq[3]) * (1.f / 256.f);
    float var = ex2 - mu * mu;
    float r = rsqrtf(var + 1e-5f);
    out[b * 256 + tid] = (v - mu) * r * ln_g[tid] + ln_b[tid];
  }
}

extern "C" void kernel_launch(void* const* d_in, const int* in_sizes, int n_in,
                              void* d_out, int out_size, void* d_ws, size_t ws_size,
                              hipStream_t stream) {
  const float* x      = (const float*)d_in[0];
  const float* rel    = (const float*)d_in[1];
  const float* w1     = (const float*)d_in[2];
  const float* b1     = (const float*)d_in[3];
  const float* w2     = (const float*)d_in[4];
  const float* b2     = (const float*)d_in[5];
  const float* Wl1    = (const float*)d_in[6];
  const float* bl1    = (const float*)d_in[7];
  const float* Wr1    = (const float*)d_in[8];
  const float* br1    = (const float*)d_in[9];
  const float* att1   = (const float*)d_in[10];
  const float* bias1  = (const float*)d_in[11];
  const float* Wl2    = (const float*)d_in[12];
  const float* bl2    = (const float*)d_in[13];
  const float* Wr2    = (const float*)d_in[14];
  const float* br2    = (const float*)d_in[15];
  const float* att2   = (const float*)d_in[16];
  const float* bias2  = (const float*)d_in[17];
  const float* ln_g   = (const float*)d_in[18];
  const float* ln_b   = (const float*)d_in[19];
  float* out = (float*)d_out;

  char* p = (char*)d_ws;
  _Float16* h0     = (_Float16*)p; p += (size_t)NN * 768 * 2;
  _Float16* h1     = (_Float16*)p; p += (size_t)NN * 512 * 2;
  _Float16* Wt1    = (_Float16*)p; p += (size_t)1024 * 768 * 2;
  _Float16* Wt2cat = (_Float16*)p; p += (size_t)512 * 512 * 2;
  _Float16* att_h  = (_Float16*)p; p += 1024;
  float* biasc     = (float*)p; p += 1024 * 4;
  _Float16* xl2    = (_Float16*)p; p += (size_t)NN * 256 * 2;
  _Float16* xr2    = (_Float16*)p; p += (size_t)BB * 256 * 2;

  prep_all<<<2560 + 1025, 256, 0, stream>>>(x, rel, w1, b1, w2, b2, Wl1, Wr1, Wl2, Wr2,
                                            bl1, br1, att1, h0, Wt1, Wt2cat, biasc, att_h);

  gemm1gat1<<<1024, 512, 0, stream>>>(h0, Wt1, biasc, att_h, bias1, h1);

  gemm2a<<<648, 256, 0, stream>>>(h1, Wt2cat, bl2, br2, xl2, xr2);

  gat2ln<<<BB, 512, 0, stream>>>(xl2, xr2, att2, bias2, ln_g, ln_b, out);
}

// Round 13
// 168.087 us; speedup vs baseline: 1.0830x; 1.0006x over previous
//
#include <hip/hip_runtime.h>
#include <hip/hip_bf16.h>

#define NN 10240
#define LL 80
#define BB 128

typedef _Float16 half8 __attribute__((ext_vector_type(8)));
typedef _Float16 half2v __attribute__((ext_vector_type(2)));
typedef float f32x4 __attribute__((ext_vector_type(4)));

#define GLD16(gptr, lptr)                                                        \
  __builtin_amdgcn_global_load_lds(                                              \
      (const __attribute__((address_space(1))) void*)(gptr),                     \
      (__attribute__((address_space(3))) void*)(lptr), 16, 0, 0)

__device__ __forceinline__ float dot2f(half2v a, half2v b, float c) {
#if __has_builtin(__builtin_amdgcn_fdot2)
  return __builtin_amdgcn_fdot2(a, b, c, false);
#else
  return c + (float)a.x * (float)b.x + (float)a.y * (float)b.y;
#endif
}
__device__ __forceinline__ half2v u2h(unsigned int u) { half2v r; __builtin_memcpy(&r, &u, 4); return r; }
__device__ __forceinline__ unsigned int h2u(half2v h) { unsigned int u; __builtin_memcpy(&u, &h, 4); return u; }
// row offset (f16 units): 144B stride -> 16B-aligned rows (b128-legal)
__device__ __forceinline__ int roff(int r) { return r * 72; }

// 4 dwords (8 ch) of logit dot with pre-hoisted att regs: acc += att . lrelu(xl + xr)
__device__ __forceinline__ float dotq4r(uint4 a, uint4 b, const half2v* atv, int qb, float acc) {
  const half2v c02 = {(_Float16)0.2f, (_Float16)0.2f};
  unsigned int aa[4] = {a.x, a.y, a.z, a.w};
  unsigned int bb[4] = {b.x, b.y, b.z, b.w};
#pragma unroll
  for (int j = 0; j < 4; ++j) {
    half2v e = u2h(aa[j]) + u2h(bb[j]);
    half2v l = __builtin_elementwise_max(e, e * c02);
    acc = dot2f(l, atv[qb + j], acc);
  }
  return acc;
}

// ================= prep_all: gate_scale (4 nodes/block, vectorized) + transposes ================
__global__ __launch_bounds__(256) void prep_all(
    const float* __restrict__ x, const float* __restrict__ rel,
    const float* __restrict__ w1, const float* __restrict__ b1,
    const float* __restrict__ w2, const float* __restrict__ b2,
    const float* __restrict__ Wl1, const float* __restrict__ Wr1,
    const float* __restrict__ Wl2, const float* __restrict__ Wr2,
    const float* __restrict__ bl1, const float* __restrict__ br1,
    const float* __restrict__ att1,
    _Float16* __restrict__ h0, _Float16* __restrict__ Wt1,
    _Float16* __restrict__ Wt2cat,
    float* __restrict__ biasc, _Float16* __restrict__ att_h) {
  __shared__ float tile[32][33];
  int bid = blockIdx.x;
  int tid = threadIdx.x;
  if (bid < 2560) {
    int wave = tid >> 6, l = tid & 63;
    int n = bid * 4 + wave;
    float r0 = rel[n * 3 + 0], r1 = rel[n * 3 + 1], r2 = rel[n * 3 + 2];
    float v = r0 * w1[l] + r1 * w1[64 + l] + r2 * w1[128 + l] + b1[l];
    v = v > 0.f ? v : 0.f;
    v *= w2[l];
    for (int d = 32; d; d >>= 1) v += __shfl_down(v, d, 64);
    float s = __shfl(v, 0, 64);
    float g = 1.f / (1.f + __expf(-(s + b2[0])));
    const float4* xr = (const float4*)(x + (size_t)n * 768);
    _Float16* hr = h0 + (size_t)n * 768;
#pragma unroll
    for (int i = 0; i < 3; ++i) {
      int f = i * 64 + l;
      float4 xv = xr[f];
      half2v p0 = {(_Float16)(xv.x * g), (_Float16)(xv.y * g)};
      half2v p1 = {(_Float16)(xv.z * g), (_Float16)(xv.w * g)};
      uint2 ov = {h2u(p0), h2u(p1)};
      *(uint2*)&hr[f * 4] = ov;
    }
    return;
  }
  int r = bid - 2560;
  const float* W;
  _Float16* Wt;
  int K, Nc, bx, by;
  if (r < 384)      { W = Wl1; Wt = Wt1;                          K = 768; Nc = 512; bx = r % 16;       by = r / 16; }
  else if (r < 768) { W = Wr1; Wt = Wt1 + (size_t)512 * 768;      K = 768; Nc = 512; bx = (r-384) % 16; by = (r-384) / 16; }
  else if (r < 896) { W = Wl2; Wt = Wt2cat;                       K = 512; Nc = 256; bx = (r-768) % 8;  by = (r-768) / 8; }
  else if (r < 1024){ W = Wr2; Wt = Wt2cat + (size_t)256 * 512;   K = 512; Nc = 256; bx = (r-896) % 8;  by = (r-896) / 8; }
  else {
    for (int i = tid; i < 1024; i += 256) biasc[i] = (i < 512) ? bl1[i] : br1[i - 512];
    for (int i = tid; i < 512; i += 256) att_h[i] = (_Float16)att1[i];
    return;
  }
  int n0 = bx * 32, k0 = by * 32;
  int c = tid & 31, rr = tid >> 5;
#pragma unroll
  for (int p = 0; p < 4; ++p) {
    int rw = p * 8 + rr;
    tile[rw][c] = W[(size_t)(k0 + rw) * Nc + n0 + c];
  }
  __syncthreads();
#pragma unroll
  for (int p = 0; p < 4; ++p) {
    int rw = p * 8 + rr;
    Wt[(size_t)(n0 + rw) * K + k0 + c] = (_Float16)tile[c][rw];
  }
}

// ================= fused gemm1 + GATv2 layer-1 (R12 base + K-SPLIT GEMM) ================
// block = (head, dialogue): h = bx>>7, b = bx&127.
// GEMM K-SPLIT (clean test of the A-redundancy model — R4/R5/R8 were confounded):
//   wave w = (n-pair g=w&3, K-half kh=w>>2). Each wave computes acc[5][2] for cols
//   {2g,2g+1} over ITS K=32 slab of each BK=64 tile: 7 LDS reads/tile (5A+2B) vs 12,
//   block 56 vs 96 (-42%), SAME 80 MFMAs, 8 computing waves, 53KB LDS, 12 barriers,
//   occupancy. Post-loop: waves 4-7 dump partials to LDS scratch (dead staging, 40KB),
//   waves 0-3 add; epilogue on waves 0-3 (2 n-tiles each). +2 barriers (one-time).
// NaN-safety: the f32 scratch tramples xlT's 88-stride K-pad with arbitrary bytes
//   (can decode as f16 NaN; 0*NaN=NaN in phase-5) -> re-zero the 520-elem pad after
//   the reduction (R9/R10 lesson).
// GAT (unchanged): logits -> softmax -> dense alpha P[80][104] -> MFMA P@xlT -> ELU -> h1.
// LDS map: staging Ab 2x5120 @0 (20480), Bb 2x8192 @20480 (32768) -> 53248.
//   scratch f32[4][64][40] @0 (40960, post-loop only, dead before epilogue writes).
//   GAT overlay: xl@0 11520, xr@11520 11520, logit@23040 4160, src8@27200 1040,
//   hub@28240 320, xlT@28560 11264 -> 39824; P overlays @0 (16640).
__global__ __launch_bounds__(512, 6) void gemm1gat1(
    const _Float16* __restrict__ h0, const _Float16* __restrict__ Wt1,
    const float* __restrict__ biasc, const _Float16* __restrict__ att_h,
    const float* __restrict__ bias1, _Float16* __restrict__ h1) {
  __shared__ __align__(16) char smem[53248];
  _Float16* Ab = (_Float16*)smem;              // 2 x 5120 f16
  _Float16* Bb = (_Float16*)(smem + 20480);    // 2 x 8192 f16
  _Float16* s_xl = (_Float16*)smem;
  _Float16* s_xr = (_Float16*)(smem + 11520);
  float* s_logit = (float*)(smem + 23040);
  signed char* s_src8 = (signed char*)(smem + 27200);
  float* s_hub = (float*)(smem + 28240);
  _Float16* s_xlT = (_Float16*)(smem + 28560);
  _Float16* s_P = (_Float16*)smem;   // overlays xl+xr after logits

  int bx = blockIdx.x;
  int h = bx >> 7, b = bx & 127;
  int base = b * LL;
  int tid = threadIdx.x;
  int wave = tid >> 6, lane = tid & 63;
  int lr = lane & 15, lk = lane >> 4;

  // ---- staging pointers: source pre-swizzled, seg = (lane&7)^((lane>>3)&7) ----
  int segA8 = ((lane & 7) ^ ((lane >> 3) & 7)) * 8;
  int r0a = wave * 16 + (lane >> 3);          // j=0 row
  const _Float16* aP0 = h0;
  const _Float16* aP1 = h0;
  if (wave < 5) {                              // A rows 0..79
    aP0 = h0 + (size_t)(base + r0a) * 768 + segA8;
    aP1 = h0 + (size_t)(base + r0a + 8) * 768 + segA8;
  }
  int rb0 = r0a, rb1 = r0a + 8;                // B rows 0..127
  int wr0 = (rb0 < 64) ? (h * 64 + rb0) : (512 + h * 64 + (rb0 - 64));
  int wr1 = (rb1 < 64) ? (h * 64 + rb1) : (512 + h * 64 + (rb1 - 64));
  const _Float16* bP0 = Wt1 + (size_t)wr0 * 768 + segA8;
  const _Float16* bP1 = Wt1 + (size_t)wr1 * 768 + segA8;

  // ---- K-split roles ----
  int g2 = wave & 3, kh = wave >> 2;
  int n0c = (2 * g2) * 16 + lr;                // col of n-tile j=0
  int n1c = (2 * g2 + 1) * 16 + lr;            // col of n-tile j=1
  int cx = ((kh * 4 + lk) ^ (lr & 7)) * 8;     // swizzled K-slot for this wave's slab

  f32x4 acc[5][2] = {};
  // prologue: stage tile 0 into buffer 0
  if (wave < 5) {
    GLD16(aP0, Ab + wave * 1024);
    GLD16(aP1, Ab + wave * 1024 + 512);
  }
  GLD16(bP0, Bb + wave * 1024);
  GLD16(bP1, Bb + wave * 1024 + 512);
  __syncthreads();
  for (int t = 0; t < 12; ++t) {
    int cur = t & 1;
    if (t < 11) {
      int k0 = (t + 1) * 64;
      int nb = cur ^ 1;
      if (wave < 5) {
        GLD16(aP0 + k0, Ab + nb * 5120 + wave * 1024);
        GLD16(aP1 + k0, Ab + nb * 5120 + wave * 1024 + 512);
      }
      GLD16(bP0 + k0, Bb + nb * 8192 + wave * 1024);
      GLD16(bP1 + k0, Bb + nb * 8192 + wave * 1024 + 512);
    }
    const _Float16* Ac = Ab + cur * 5120;
    const _Float16* Bc = Bb + cur * 8192;
    half8 bf0 = *(const half8*)(Bc + n0c * 64 + cx);
    half8 bf1 = *(const half8*)(Bc + n1c * 64 + cx);
#pragma unroll
    for (int m = 0; m < 5; ++m) {
      half8 af = *(const half8*)(Ac + (m * 16 + lr) * 64 + cx);
      acc[m][0] = __builtin_amdgcn_mfma_f32_16x16x32_f16(af, bf0, acc[m][0], 0, 0, 0);
      acc[m][1] = __builtin_amdgcn_mfma_f32_16x16x32_f16(af, bf1, acc[m][1], 0, 0, 0);
    }
    __syncthreads();
  }
  // ---- K-half reduction: waves 4-7 store partials, waves 0-3 add ----
  {
    float* scr = (float*)smem;
    if (wave >= 4) {
      int bi = ((wave - 4) * 64 + lane) * 40;
#pragma unroll
      for (int m = 0; m < 5; ++m)
#pragma unroll
        for (int j = 0; j < 2; ++j)
          *(f32x4*)(scr + bi + (m * 2 + j) * 4) = acc[m][j];
    }
    __syncthreads();
    if (wave < 4) {
      int bi = (wave * 64 + lane) * 40;
#pragma unroll
      for (int m = 0; m < 5; ++m)
#pragma unroll
        for (int j = 0; j < 2; ++j)
          acc[m][j] += *(const f32x4*)(scr + bi + (m * 2 + j) * 4);
    }
    __syncthreads();
  }
  // ---- NaN fix: scratch trampled xlT region with f32 bytes (can decode as f16 NaN).
  //      Zero the K-pad cols [80,88) of all 64 rows + the row-64 overflow slot.
  {
    int z = tid;
    if (z < 512) s_xlT[(z >> 3) * 88 + 80 + (z & 7)] = (_Float16)0.f;
    if (z < 8) s_xlT[64 * 88 + z] = (_Float16)0.f;
  }
  // ---- epilogue: waves 0-3 write both n-tiles' xl/xr (+bias) + xlT; adjacency build ----
  if (wave < 4) {
#pragma unroll
    for (int j = 0; j < 2; ++j) {
      int c = (wave * 2 + j) * 16 + lr;          // 0..127
      bool isxl = c < 64;
      int cc = isxl ? c : c - 64;
      float bb = biasc[(isxl ? 0 : 512) + h * 64 + cc];
      _Float16* dst = isxl ? s_xl : s_xr;
#pragma unroll
      for (int m = 0; m < 5; ++m)
#pragma unroll
        for (int rg = 0; rg < 4; ++rg) {
          int row = m * 16 + lk * 4 + rg;
          _Float16 hv = (_Float16)(acc[m][j][rg] + bb);
          dst[roff(row) + cc] = hv;
          if (isxl) s_xlT[cc * 88 + row] = hv;
        }
    }
  }
  if (tid < 79) {
    int d = tid;
    signed char list[13];
    int c = 0;
    list[c++] = (signed char)d;
    if (d > 0) list[c++] = (signed char)(d - 1);
    if (d + 1 < 79) list[c++] = (signed char)(d + 1);
    list[c++] = 79;
    for (int j = d & 7; j < 80; j += 8)
      if (j != d && j != 79) list[c++] = (signed char)j;
    for (int i = c; i < 13; ++i) list[i] = -1;
#pragma unroll
    for (int i = 0; i < 13; ++i) s_src8[i * 80 + d] = list[i];
  }
  __syncthreads();

  // ---- edge logits: dst-grouped, att hoisted to SGPR, xr cached in regs, xl as b128 ----
  const unsigned int* pat = (const unsigned int*)(att_h + h * 64);
  half2v atv[32];
#pragma unroll
  for (int q = 0; q < 32; ++q) atv[q] = u2h(__builtin_amdgcn_readfirstlane(pat[q]));
  if (tid < 474) {
    int d = tid / 6, io = tid % 6;
    const uint4* pxr = (const uint4*)(s_xr + roff(d));
    uint4 xrr[8];
#pragma unroll
    for (int q = 0; q < 8; ++q) xrr[q] = pxr[q];
#pragma unroll
    for (int k = 0; k < 3; ++k) {
      int i = io + 6 * k;
      if (i < 13) {
        int src = s_src8[i * 80 + d];
        if (src < 0) {
          s_logit[i * 80 + d] = -3e38f;
        } else {
          const uint4* pxl = (const uint4*)(s_xl + roff(src));
          float a2 = 0.f;
#pragma unroll
          for (int q = 0; q < 8; ++q) a2 = dotq4r(pxl[q], xrr[q], atv, q * 4, a2);
          s_logit[i * 80 + d] = a2;
        }
      }
    }
  } else {
    int j = tid - 474;
    const uint4* pxr = (const uint4*)(s_xr + roff(79));
    uint4 xrr[8];
#pragma unroll
    for (int q = 0; q < 8; ++q) xrr[q] = pxr[q];
#pragma unroll
    for (int k = 0; k < 3; ++k) {
      int s = j + 38 * k;
      if (s < 80) {
        const uint4* pxl = (const uint4*)(s_xl + roff(s));
        float a2 = 0.f;
#pragma unroll
        for (int q = 0; q < 8; ++q) a2 = dotq4r(pxl[q], xrr[q], atv, q * 4, a2);
        s_hub[s] = a2;
      }
    }
  }
  __syncthreads();

  // ---- phase 3: zero dense P + compute alphas into regs ----
  {
    uint4 z4 = {0u, 0u, 0u, 0u};
    for (int z = tid; z < 1040; z += 512) ((uint4*)smem)[z] = z4;  // P [0,16640)
  }
  float va[13], inv_d = 0.f;
  bool isd = tid < 79;
  if (isd) {
    int d = tid;
    float m = -3e38f;
#pragma unroll
    for (int i = 0; i < 13; ++i) { va[i] = s_logit[i * 80 + d]; m = fmaxf(m, va[i]); }
    float sum = 0.f;
#pragma unroll
    for (int i = 0; i < 13; ++i) { va[i] = __expf(va[i] - m); sum += va[i]; }
    inv_d = 1.f / sum;
  }
  float he0 = 0.f, he1 = 0.f, hinv = 0.f;
  if (wave == 7) {
    int l = lane;
    float v0 = s_hub[l];
    float v1 = (l < 16) ? s_hub[64 + l] : -3e38f;
    float m = fmaxf(v0, v1);
    for (int d = 32; d; d >>= 1) m = fmaxf(m, __shfl_xor(m, d, 64));
    he0 = __expf(v0 - m);
    he1 = (l < 16) ? __expf(v1 - m) : 0.f;
    float sum = he0 + he1;
    for (int d = 32; d; d >>= 1) sum += __shfl_xor(sum, d, 64);
    hinv = 1.f / sum;
  }
  __syncthreads();

  // ---- phase 4: scatter alphas into P (f16) ----
  if (isd) {
    int d = tid;
#pragma unroll
    for (int i = 0; i < 13; ++i) {
      int src = s_src8[i * 80 + d];
      if (src >= 0) s_P[d * 104 + src] = (_Float16)(va[i] * inv_d);
    }
  }
  if (wave == 7) {
    int l = lane;
    s_P[79 * 104 + l] = (_Float16)(he0 * hinv);
    if (l < 16) s_P[79 * 104 + 64 + l] = (_Float16)(he1 * hinv);
  }
  __syncthreads();

  // ---- phase 5: MFMA aggregation out[80x64] = P[80x80(pad96)] @ xlT^T; ELU; h1 ----
  {
    int nt = (wave < 4) ? 3 : 2;
    int tb = (wave < 4) ? wave * 3 : 12 + (wave - 4) * 2;
    for (int tt = 0; tt < nt; ++tt) {
      int t = tb + tt;
      int m = t >> 2, n = t & 3;   // m 0..4, n 0..3
      f32x4 a = {};
#pragma unroll
      for (int kc = 0; kc < 3; ++kc) {
        half8 af = *(const half8*)(s_P + (m * 16 + lr) * 104 + kc * 32 + lk * 8);
        half8 bf = *(const half8*)(s_xlT + (n * 16 + lr) * 88 + kc * 32 + lk * 8);
        a = __builtin_amdgcn_mfma_f32_16x16x32_f16(af, bf, a, 0, 0, 0);
      }
      int c = n * 16 + lr;
      float bb = bias1[h * 64 + c];
#pragma unroll
      for (int rg = 0; rg < 4; ++rg) {
        int d = m * 16 + lk * 4 + rg;   // < 80
        float v = a[rg] + bb;
        v = v > 0.f ? v : __expf(v) - 1.f;
        h1[(size_t)(base + d) * 512 + h * 64 + c] = (_Float16)v;
      }
    }
  }
}

// ================= gemm2a: xl2 = h1@Wl2+bl2 (640 blocks) AND xr2 = h1[last]@Wr2+br2 (8 blocks)
__global__ __launch_bounds__(256) void gemm2a(
    const _Float16* __restrict__ h1, const _Float16* __restrict__ Bt,
    const float* __restrict__ bl2, const float* __restrict__ br2,
    _Float16* __restrict__ xl2, _Float16* __restrict__ xr2) {
  __shared__ __align__(16) char smem[16384];
  _Float16* Ab = (_Float16*)smem;            // 2 x 2048 f16
  _Float16* Bb = (_Float16*)(smem + 8192);   // 2 x 2048 f16
  int bx = blockIdx.x;
  bool isxr = bx >= 640;
  int bl = isxr ? bx - 640 : bx;
  int mb = bl >> 2, nb = bl & 3;
  int tid = threadIdx.x;
  int wave = tid >> 6, lane = tid & 63;
  int lr = lane & 15, lk = lane >> 4;
  int seg8 = ((lane & 3) ^ ((lane >> 3) & 3)) * 8;
  int row = tid >> 2;               // 0..63
  size_t arow = isxr ? ((size_t)(mb * 64 + row) * 80 + 79) : (size_t)(mb * 64 + row);
  const _Float16* aP = h1 + arow * 512 + seg8;
  const _Float16* bP = Bt + (size_t)((isxr ? 256 : 0) + nb * 64 + row) * 512 + seg8;
  int xk8 = (lk ^ ((lr >> 1) & 3)) * 8;
  f32x4 acc[4] = {};
  GLD16(aP, Ab + wave * 512);
  GLD16(bP, Bb + wave * 512);
  __syncthreads();
  for (int t = 0; t < 16; ++t) {
    int cur = t & 1;
    if (t < 15) {
      int k0 = (t + 1) * 32;
      int nbuf = cur ^ 1;
      GLD16(aP + k0, Ab + nbuf * 2048 + wave * 512);
      GLD16(bP + k0, Bb + nbuf * 2048 + wave * 512);
    }
    const _Float16* Ac = Ab + cur * 2048;
    const _Float16* Bc = Bb + cur * 2048;
    half8 bf = *(const half8*)(Bc + (wave * 16 + lr) * 32 + xk8);
#pragma unroll
    for (int m = 0; m < 4; ++m) {
      half8 af = *(const half8*)(Ac + (m * 16 + lr) * 32 + xk8);
      acc[m] = __builtin_amdgcn_mfma_f32_16x16x32_f16(af, bf, acc[m], 0, 0, 0);
    }
    __syncthreads();
  }
  int col = nb * 64 + wave * 16 + lr;
  float bb = isxr ? br2[col] : bl2[col];
  _Float16* dst = isxr ? xr2 : xl2;
#pragma unroll
  for (int m = 0; m < 4; ++m)
#pragma unroll
    for (int rg = 0; rg < 4; ++rg) {
      int r = mb * 64 + m * 16 + lk * 4 + rg;
      dst[(size_t)r * 256 + col] = (_Float16)(acc[m][rg] + bb);
    }
}

// ================= gat2ln: per-dialogue attention + LN (xr precomputed in gemm2a) ========
#define PX 264
__global__ __launch_bounds__(512) void gat2ln(
    const _Float16* __restrict__ xl2, const _Float16* __restrict__ xr2,
    const float* __restrict__ att2, const float* __restrict__ bias2,
    const float* __restrict__ ln_g, const float* __restrict__ ln_b,
    float* __restrict__ out) {
  __shared__ __align__(16) _Float16 s_x[80 * PX];   // 42240 B
  __shared__ _Float16 s_att[256];
  __shared__ _Float16 s_xr[256];
  __shared__ float s_red[80];
  __shared__ float s_sum[4], s_sq[4];

  int b = blockIdx.x;
  int tid = threadIdx.x;
  int wave = tid >> 6, lane = tid & 63;

  if (tid < 256) s_att[tid] = (_Float16)att2[tid];
  // stage xl2[b] (80x256 f16) into s_x [80][PX] via b128
  for (int t = tid; t < 2560; t += 512) {
    int row = t >> 5, q = t & 31;
    uint4 v = *(const uint4*)(xl2 + ((size_t)(b * 80 + row)) * 256 + q * 8);
    *(uint4*)(s_x + row * PX + q * 8) = v;
  }
  // xr row: precomputed by gemm2a's xr blocks — 512B coalesced load
  if (tid < 256) s_xr[tid] = xr2[(size_t)b * 256 + tid];
  __syncthreads();
  if (tid < 160) {
    int r = tid >> 1, hf = tid & 1;
    const half2v* xa = (const half2v*)(s_x + r * PX + hf * 128);
    const half2v* xr = (const half2v*)(s_xr + hf * 128);
    const half2v* at = (const half2v*)(s_att + hf * 128);
    float lg = 0.f;
    const half2v c02 = {(_Float16)0.2f, (_Float16)0.2f};
#pragma unroll
    for (int q = 0; q < 64; ++q) {
      half2v e = xa[q] + xr[q];
      half2v l = __builtin_elementwise_max(e, e * c02);
      lg = dot2f(l, at[q], lg);
    }
    lg += __shfl_xor(lg, 1, 64);
    if (hf == 0) s_red[r] = lg;
  }
  __syncthreads();
  if (wave == 7) {
    float v0 = s_red[lane];
    float v1 = (lane < 16) ? s_red[64 + lane] : -3e38f;
    float m = fmaxf(v0, v1);
    for (int d = 32; d; d >>= 1) m = fmaxf(m, __shfl_xor(m, d, 64));
    float e0 = __expf(v0 - m);
    float e1 = (lane < 16) ? __expf(v1 - m) : 0.f;
    float sum = e0 + e1;
    for (int d = 32; d; d >>= 1) sum += __shfl_xor(sum, d, 64);
    float inv = 1.f / sum;
    s_red[lane] = e0 * inv;
    if (lane < 16) s_red[64 + lane] = e1 * inv;
  }
  __syncthreads();
  float v = 0.f;
  if (tid < 256) {
    float a = 0.f;
#pragma unroll
    for (int r = 0; r < 80; ++r) a += s_red[r] * (float)s_x[r * PX + tid];
    v = a + bias2[tid];
    float p = v;
    for (int d = 32; d; d >>= 1) p += __shfl_down(p, d, 64);
    if (lane == 0) s_sum[wave] = p;
    float q = v * v;
    for (int d = 32; d; d >>= 1) q += __shfl_down(q, d, 64);
    if (lane == 0) s_sq[wave] = q;
  }
  __syncthreads();
  if (tid < 256) {
    float mu = (s_sum[0] + s_sum[1] + s_sum[2] + s_sum[3]) * (1.f / 256.f);
    float ex2 = (s_sq[0] + s_sq[1] + s_sq[2] + s_sq[3]) * (1.f / 256.f);
    float var = ex2 - mu * mu;
    float r = rsqrtf(var + 1e-5f);
    out[b * 256 + tid] = (v - mu) * r * ln_g[tid] + ln_b[tid];
  }
}

extern "C" void kernel_launch(void* const* d_in, const int* in_sizes, int n_in,
                              void* d_out, int out_size, void* d_ws, size_t ws_size,
                              hipStream_t stream) {
  const float* x      = (const float*)d_in[0];
  const float* rel    = (const float*)d_in[1];
  const float* w1     = (const float*)d_in[2];
  const float* b1     = (const float*)d_in[3];
  const float* w2     = (const float*)d_in[4];
  const float* b2     = (const float*)d_in[5];
  const float* Wl1    = (const float*)d_in[6];
  const float* bl1    = (const float*)d_in[7];
  const float* Wr1    = (const float*)d_in[8];
  const float* br1    = (const float*)d_in[9];
  const float* att1   = (const float*)d_in[10];
  const float* bias1  = (const float*)d_in[11];
  const float* Wl2    = (const float*)d_in[12];
  const float* bl2    = (const float*)d_in[13];
  const float* Wr2    = (const float*)d_in[14];
  const float* br2    = (const float*)d_in[15];
  const float* att2   = (const float*)d_in[16];
  const float* bias2  = (const float*)d_in[17];
  const float* ln_g   = (const float*)d_in[18];
  const float* ln_b   = (const float*)d_in[19];
  float* out = (float*)d_out;

  char* p = (char*)d_ws;
  _Float16* h0     = (_Float16*)p; p += (size_t)NN * 768 * 2;
  _Float16* h1     = (_Float16*)p; p += (size_t)NN * 512 * 2;
  _Float16* Wt1    = (_Float16*)p; p += (size_t)1024 * 768 * 2;
  _Float16* Wt2cat = (_Float16*)p; p += (size_t)512 * 512 * 2;
  _Float16* att_h  = (_Float16*)p; p += 1024;
  float* biasc     = (float*)p; p += 1024 * 4;
  _Float16* xl2    = (_Float16*)p; p += (size_t)NN * 256 * 2;
  _Float16* xr2    = (_Float16*)p; p += (size_t)BB * 256 * 2;

  prep_all<<<2560 + 1025, 256, 0, stream>>>(x, rel, w1, b1, w2, b2, Wl1, Wr1, Wl2, Wr2,
                                            bl1, br1, att1, h0, Wt1, Wt2cat, biasc, att_h);

  gemm1gat1<<<1024, 512, 0, stream>>>(h0, Wt1, biasc, att_h, bias1, h1);

  gemm2a<<<648, 256, 0, stream>>>(h1, Wt2cat, bl2, br2, xl2, xr2);

  gat2ln<<<BB, 512, 0, stream>>>(xl2, xr2, att2, bias2, ln_g, ln_b, out);
}